// Round 9
// baseline (528.699 us; speedup 1.0000x reference)
//
#include <hip/hip_runtime.h>
#include <hip/hip_bf16.h>

#define EPSBN 1e-3f

typedef __attribute__((ext_vector_type(8))) short bf16x8;
typedef __attribute__((ext_vector_type(8))) unsigned short ushort8;
typedef __attribute__((ext_vector_type(4))) float f32x4;

// ---------------------------------------------------------------------------
//   x    : (16, 64, 49, 1024) f32
//   extb : (16, 2, 64, 1024)  bf16   [slot 0: max over s, slot 1: mean]
//   zb2  : (16, 32, 53, 1280) bf16   GROUP-MAJOR ch = g0*160 + (p*32+n);
//                                    s<51 by layer0, s=51,52 by reduce1
//   W0t  : bf16 [8 g][160 n][128 k]
//   W1t  : bf16 [8 g][200 n][160 k-permuted] (kref = (k%20)*8 + k/20)
//   og   : (16, 16, 53, 1600) bf16   group-major layer1 output
//   out  : (16, 16, 53, 1600) f32    ref channel order (pq*8+g), by tc_shuffle
// ---------------------------------------------------------------------------

__device__ __forceinline__ float bf2f(unsigned short u) {
    union { unsigned int i; float f; } c; c.i = (unsigned int)u << 16; return c.f;
}
__device__ __forceinline__ unsigned short f2bf(float f) {
    union { float f; unsigned int i; } c; c.f = f;
    unsigned int r = c.i + 0x7FFF + ((c.i >> 16) & 1);   // RNE
    return (unsigned short)(r >> 16);
}

// ---------------------------------------------------------------------------
// Combined: blocks 0..1023 = reduce0 (max/mean over s -> extb);
//           blocks 1024..2663 = weight transpose prep.
// ---------------------------------------------------------------------------
__global__ __launch_bounds__(256) void tc_prep_reduce0(
    const float* __restrict__ x, unsigned short* __restrict__ extb,
    const float* __restrict__ w0, const float* __restrict__ w1,
    unsigned short* __restrict__ W0t, unsigned short* __restrict__ W1t)
{
    if (blockIdx.x < 1024) {
        const int bt = blockIdx.x;              // b*64+t
        const int b  = bt >> 6, t = bt & 63;
        const int c  = threadIdx.x * 4;
        const float4* src = reinterpret_cast<const float4*>(x + (size_t)bt * 49 * 1024 + c);
        float4 v = src[0];
        float mx0 = v.x, mx1 = v.y, mx2 = v.z, mx3 = v.w;
        float sm0 = v.x, sm1 = v.y, sm2 = v.z, sm3 = v.w;
        for (int s = 1; s < 49; ++s) {
            float4 u = src[(size_t)s * 256];
            mx0 = fmaxf(mx0, u.x); sm0 += u.x;
            mx1 = fmaxf(mx1, u.y); sm1 += u.y;
            mx2 = fmaxf(mx2, u.z); sm2 += u.z;
            mx3 = fmaxf(mx3, u.w); sm3 += u.w;
        }
        const float inv = 1.0f / 49.0f;
        ushort4 omx, omn;
        omx.x=f2bf(mx0); omx.y=f2bf(mx1); omx.z=f2bf(mx2); omx.w=f2bf(mx3);
        omn.x=f2bf(sm0*inv); omn.y=f2bf(sm1*inv); omn.z=f2bf(sm2*inv); omn.w=f2bf(sm3*inv);
        *reinterpret_cast<ushort4*>(&extb[((size_t)(b*2 + 0)*64 + t)*1024 + c]) = omx;
        *reinterpret_cast<ushort4*>(&extb[((size_t)(b*2 + 1)*64 + t)*1024 + c]) = omn;
    } else {
        const int idx = (blockIdx.x - 1024) * 256 + threadIdx.x;
        if (idx < 163840) {                         // 8*160*128
            const int g   = idx / 20480;
            const int rem = idx - g*20480;
            const int n   = rem >> 7;
            const int k   = rem & 127;
            const int p   = n >> 5, nn = n & 31;
            W0t[idx] = f2bf(w0[(((size_t)p*8 + g)*128 + k)*32 + nn]);
        } else if (idx < 163840 + 256000) {         // 8*200*160
            const int i2  = idx - 163840;
            const int g   = i2 / 32000;
            const int rem = i2 - g*32000;
            const int n   = rem / 160;
            const int k   = rem - n*160;
            const int kref = (k % 20)*8 + k/20;
            const int p   = n / 40, nn = n - p*40;
            W1t[i2] = f2bf(w1[(((size_t)p*8 + g)*160 + kref)*40 + nn]);
        }
    }
}

// ---------------------------------------------------------------------------
// Layer 0: block (b, s-pair, g).  M = 128 rows = 2 s-columns x 64 t.
// 8 waves (512 thr); epilogue split per t-half (yw[40] halo window) so VGPR
// fits the (512,6) budget -> 3 blocks/CU.
// ---------------------------------------------------------------------------
__global__ __launch_bounds__(512, 6) void tc_layer0(
    const float* __restrict__ x, const unsigned short* __restrict__ extb,
    const unsigned short* __restrict__ W0t, const float* __restrict__ bias,
    const float* __restrict__ k3, const float* __restrict__ k5,
    const float* __restrict__ k7,
    const float* __restrict__ gam, const float* __restrict__ bet,
    const float* __restrict__ mu, const float* __restrict__ var,
    unsigned short* __restrict__ zb)
{
    const int tid = threadIdx.x;
    const int g   = blockIdx.x / 416;       // 416 = 16 b * 26 s-pairs; 416%8==0
    const int rem = blockIdx.x % 416;
    const int sp  = rem % 26;
    const int b   = rem / 26;
    const int s0  = sp*2;
    const int has1 = (s0 + 1 < 51);

    __shared__ __align__(16) unsigned short lds[128*136 + 160*40];  // 23808 u16 = 47.6KB
    unsigned short* AtU = lds;              // [128][136] bf16 (rows 0-63: s0, 64-127: s1)
    unsigned short* WtU = lds + 128*136;    // [160][40] bf16 (32-k chunk)
    unsigned short* Ytb = lds;              // [160][134] bf16 overlay (21440 u16)

    // ---- stage At (128 rows x 128 k) f32 -> bf16 (ext rows from extb) ----
    #pragma unroll
    for (int it = 0; it < 4; ++it) {
        const int fid = tid + it*512;           // < 2048
        const int row = fid >> 4;
        const int ch8 = (fid & 15) * 8;
        const int t   = row & 63;
        const int s   = (row < 64) ? s0 : (has1 ? s0+1 : s0);
        ushort8 u;
        if (s < 49) {
            const float* sp_ = x + ((size_t)(b*64 + t)*49 + s)*1024 + g*128 + ch8;
            const float4 f0 = *reinterpret_cast<const float4*>(sp_);
            const float4 f1 = *reinterpret_cast<const float4*>(sp_ + 4);
            u[0]=f2bf(f0.x); u[1]=f2bf(f0.y); u[2]=f2bf(f0.z); u[3]=f2bf(f0.w);
            u[4]=f2bf(f1.x); u[5]=f2bf(f1.y); u[6]=f2bf(f1.z); u[7]=f2bf(f1.w);
        } else {
            u = *reinterpret_cast<const ushort8*>(
                &extb[((size_t)(b*2 + (s-49))*64 + t)*1024 + g*128 + ch8]);
        }
        *reinterpret_cast<ushort8*>(&AtU[row*136 + ch8]) = u;
    }

    const int lane = tid & 63;
    const int wid  = tid >> 6;              // t-tile 0..7 over M=128
    const int fr   = lane & 15;
    const int kb   = lane >> 4;

    f32x4 zero = {0.f, 0.f, 0.f, 0.f};
    f32x4 acc[10];
    #pragma unroll
    for (int i = 0; i < 10; ++i) acc[i] = zero;

    for (int kc = 0; kc < 4; ++kc) {
        __syncthreads();
        #pragma unroll
        for (int it = 0; it < 2; ++it) {        // stage 160 n x 32 k
            const int gi = tid + it*512;        // < 640
            if (gi < 640) {
                const int n = gi >> 2, part = (gi & 3) * 8;
                *reinterpret_cast<ushort8*>(&WtU[n*40 + part]) =
                    *reinterpret_cast<const ushort8*>(
                        &W0t[((size_t)g*160 + n)*128 + kc*32 + part]);
            }
        }
        __syncthreads();
        const bf16x8 bfrag = *reinterpret_cast<const bf16x8*>(
            &AtU[(wid*16 + fr)*136 + kc*32 + kb*8]);
        #pragma unroll
        for (int nt = 0; nt < 10; ++nt) {
            const bf16x8 afrag = *reinterpret_cast<const bf16x8*>(
                &WtU[(nt*16 + fr)*40 + kb*8]);
            acc[nt] = __builtin_amdgcn_mfma_f32_16x16x32_bf16(afrag, bfrag, acc[nt], 0, 0, 0);
        }
    }
    __syncthreads();
    // D: row(n) = nt*16 + kb*4 + r, col = wid*16 + fr  (cols 0-63: s0, 64-127: s1)
    #pragma unroll
    for (int nt = 0; nt < 10; ++nt)
        #pragma unroll
        for (int r = 0; r < 4; ++r)
            Ytb[(nt*16 + kb*4 + r)*134 + wid*16 + fr] = f2bf(acc[nt][r]);
    __syncthreads();

    // ---- epilogue: 640 tasks = 160 ch x 2 s x 2 t-halves ----
    #pragma unroll
    for (int it2 = 0; it2 < 2; ++it2) {
        const int task = tid + it2*512;
        if (task < 640) {
            const int ch   = task % 160;
            const int rest = task / 160;        // 0..3
            const int sIdx = rest >> 1;
            const int th   = rest & 1;
            if (!sIdx || has1) {
                const int s  = s0 + sIdx;
                const int p  = ch >> 5, n = ch & 31;
                const int pi = (p*8 + g)*32 + n;
                const float bsv = bias[pi];
                const float sc  = gam[pi]*rsqrtf(var[pi]+EPSBN);
                const float sh  = bet[pi] - mu[pi]*sc;
                const int t0 = th*32 - 4;       // window [t0, t0+40)
                float yw[40];
                #pragma unroll
                for (int i = 0; i < 40; i += 2) {
                    const int t = t0 + i;
                    if (t >= 0 && t < 64) {
                        const unsigned int w2 = *reinterpret_cast<const unsigned int*>(
                            &Ytb[ch*134 + sIdx*64 + t]);
                        yw[i]   = bf2f((unsigned short)(w2 & 0xffffu)) + bsv;
                        yw[i+1] = bf2f((unsigned short)(w2 >> 16)) + bsv;
                    } else { yw[i] = 0.f; yw[i+1] = 0.f; }
                }
                unsigned short* zp = zb + ((size_t)(b*32)*53 + s)*1280 + g*160 + ch;
                const int tqb = th*16;
                if (p == 0) {
                    #pragma unroll
                    for (int q2 = 0; q2 < 16; ++q2) {
                        const float r = fmaxf(fmaxf(fmaf(yw[2*q2+4],sc,sh),
                                                    fmaf(yw[2*q2+5],sc,sh)), 0.f);
                        zp[(size_t)(tqb+q2)*67840] = f2bf(r);
                    }
                } else if (p == 4) {
                    #pragma unroll
                    for (int q2 = 0; q2 < 16; ++q2) {
                        const int tq = tqb + q2;
                        const float v0 = fmaxf(yw[2*q2+4], yw[2*q2+5]);
                        const float vb = (2*tq+2 < 64) ? yw[2*q2+6] : yw[35];
                        const float v1 = fmaxf(yw[2*q2+5], vb);
                        const float r = fmaxf(fmaxf(fmaf(v0,sc,sh), fmaf(v1,sc,sh)), 0.f);
                        zp[(size_t)tq*67840] = f2bf(r);
                    }
                } else {
                    float wk[7];
                    int klen, off;
                    if (p == 1) { klen = 3; off = 1;
                        #pragma unroll
                        for (int j = 0; j < 3; ++j) wk[j] = k3[(g*32+n)*3+j];
                    } else if (p == 2) { klen = 5; off = 2;
                        #pragma unroll
                        for (int j = 0; j < 5; ++j) wk[j] = k5[(g*32+n)*5+j];
                    } else { klen = 7; off = 3;
                        #pragma unroll
                        for (int j = 0; j < 7; ++j) wk[j] = k7[(g*32+n)*7+j];
                    }
                    #pragma unroll
                    for (int q2 = 0; q2 < 16; ++q2) {
                        const int tq = tqb + q2;
                        float vv[2];
                        #pragma unroll
                        for (int q = 0; q < 2; ++q) {
                            const int t = 2*tq + q;
                            float v = 0.f;
                            for (int j = 0; j < 7; ++j) {
                                if (j < klen) {
                                    const int tt = t + j - off;
                                    if (tt >= 0 && tt < 64)
                                        v = fmaf(yw[2*q2 + 4 + q + j - off], wk[j], v);
                                }
                            }
                            vv[q] = v;
                        }
                        const float r = fmaxf(fmaxf(fmaf(vv[0],sc,sh), fmaf(vv[1],sc,sh)), 0.f);
                        zp[(size_t)tq*67840] = f2bf(r);
                    }
                }
            }
        }
    }
}

// ---------------------------------------------------------------------------
// reduce1: fills zb2 columns s=51 (max) and s=52 (mean) per (b,tq) row.
// ---------------------------------------------------------------------------
__global__ __launch_bounds__(320) void tc_reduce1(unsigned short* __restrict__ zb) {
    const int bt = blockIdx.x;              // b*32+tq
    const int c  = threadIdx.x * 4;         // 0..1276
    unsigned short* base = zb + (size_t)bt * 67840;
    ushort4 u = *reinterpret_cast<const ushort4*>(&base[c]);
    float v0 = bf2f(u.x), v1 = bf2f(u.y), v2 = bf2f(u.z), v3 = bf2f(u.w);
    float mx0 = v0, mx1 = v1, mx2 = v2, mx3 = v3;
    float sm0 = v0, sm1 = v1, sm2 = v2, sm3 = v3;
    for (int s = 1; s < 51; ++s) {
        ushort4 w = *reinterpret_cast<const ushort4*>(&base[(size_t)s*1280 + c]);
        v0 = bf2f(w.x); v1 = bf2f(w.y); v2 = bf2f(w.z); v3 = bf2f(w.w);
        mx0 = fmaxf(mx0, v0); sm0 += v0;
        mx1 = fmaxf(mx1, v1); sm1 += v1;
        mx2 = fmaxf(mx2, v2); sm2 += v2;
        mx3 = fmaxf(mx3, v3); sm3 += v3;
    }
    const float inv = 1.0f / 51.0f;
    ushort4 o;
    o.x = f2bf(mx0); o.y = f2bf(mx1); o.z = f2bf(mx2); o.w = f2bf(mx3);
    *reinterpret_cast<ushort4*>(&base[(size_t)51*1280 + c]) = o;
    o.x = f2bf(sm0*inv); o.y = f2bf(sm1*inv); o.z = f2bf(sm2*inv); o.w = f2bf(sm3*inv);
    *reinterpret_cast<ushort4*>(&base[(size_t)52*1280 + c]) = o;
}

// ---------------------------------------------------------------------------
// Layer 1: block (b, s-quad, g).  M = 128 rows = 4 s-columns x 32 t.
// ---------------------------------------------------------------------------
__global__ __launch_bounds__(512, 4) void tc_layer1(
    const unsigned short* __restrict__ zbi,
    const unsigned short* __restrict__ W1t, const float* __restrict__ bias,
    const float* __restrict__ k3, const float* __restrict__ k5,
    const float* __restrict__ k7,
    const float* __restrict__ gam, const float* __restrict__ bet,
    const float* __restrict__ mu, const float* __restrict__ var,
    unsigned short* __restrict__ og)
{
    const int tid = threadIdx.x;
    const int g   = blockIdx.x / 224;       // 224 = 16 b * 14 s-quads; 224%8==0
    const int rem = blockIdx.x % 224;
    const int sq  = rem % 14;
    const int b   = rem / 14;
    const int s0  = sq*4;
    const int ns  = (53 - s0 < 4) ? (53 - s0) : 4;

    __shared__ __align__(16) unsigned short lds[128*168 + 208*40];  // 29824 u16 = 58.3 KB
    unsigned short* AtU = lds;              // [128][168] bf16 (rows: sLocal*32 + t)
    unsigned short* WtU = lds + 128*168;    // [208][40] bf16 (rows 200-207 zero)
    unsigned short* Ytb = lds;              // [200][134] bf16 overlay (26800 u16)

    if (tid < 40) {
        ushort8 z8 = {0,0,0,0,0,0,0,0};
        const int r = tid / 5, cp = tid - r*5;
        *reinterpret_cast<ushort8*>(&WtU[(200 + r)*40 + cp*8]) = z8;
    }

    // ---- gather At (128 rows x 160 k, z0g k-order) ----
    #pragma unroll
    for (int it = 0; it < 10; ++it) {
        const int fid = tid + it*512;           // < 5120
        const int row = fid / 40;
        const int seg = fid - row*40;
        const int gg  = seg / 5, q = seg - gg*5;
        const int ch  = gg*160 + g*20 + q*4;
        const int sl  = row >> 5;
        const int s   = s0 + ((sl < ns) ? sl : 0);
        const int t   = row & 31;
        const unsigned short* src = zbi + ((size_t)(b*32 + t)*53 + s)*1280 + ch;
        *reinterpret_cast<ushort4*>(&AtU[row*168 + seg*4]) =
            *reinterpret_cast<const ushort4*>(src);
    }

    const int lane = tid & 63;
    const int wid  = tid >> 6;              // t-tile 0..7 over M=128
    const int fr   = lane & 15;
    const int kb   = lane >> 4;

    f32x4 zero = {0.f, 0.f, 0.f, 0.f};
    f32x4 acc[13];
    #pragma unroll
    for (int i = 0; i < 13; ++i) acc[i] = zero;

    for (int kc = 0; kc < 5; ++kc) {
        __syncthreads();
        #pragma unroll
        for (int it = 0; it < 2; ++it) {        // stage 200 n x 32 k
            const int gi = tid + it*512;        // < 800
            if (gi < 800) {
                const int n = gi >> 2, part = (gi & 3) * 8;
                *reinterpret_cast<ushort8*>(&WtU[n*40 + part]) =
                    *reinterpret_cast<const ushort8*>(
                        &W1t[((size_t)g*200 + n)*160 + kc*32 + part]);
            }
        }
        __syncthreads();
        const bf16x8 bfrag = *reinterpret_cast<const bf16x8*>(
            &AtU[(wid*16 + fr)*168 + kc*32 + kb*8]);
        #pragma unroll
        for (int nt = 0; nt < 13; ++nt) {
            const bf16x8 afrag = *reinterpret_cast<const bf16x8*>(
                &WtU[(nt*16 + fr)*40 + kb*8]);
            acc[nt] = __builtin_amdgcn_mfma_f32_16x16x32_bf16(afrag, bfrag, acc[nt], 0, 0, 0);
        }
    }
    __syncthreads();
    #pragma unroll
    for (int nt = 0; nt < 13; ++nt) {
        #pragma unroll
        for (int r = 0; r < 4; ++r) {
            const int n = nt*16 + kb*4 + r;
            if (n < 200) Ytb[n*134 + wid*16 + fr] = f2bf(acc[nt][r]);
        }
    }
    __syncthreads();

    // ---- epilogue: 800 tasks = 200 ch x 4 s ----
    #pragma unroll
    for (int it = 0; it < 2; ++it) {
        const int task = tid + it*512;
        if (task < 800) {
            const int sIdx = task / 200;
            const int ch   = task - sIdx*200;
            if (sIdx < ns) {
                const int s  = s0 + sIdx;
                const int p  = ch / 40, n = ch - p*40;
                const int pi = (p*8 + g)*40 + n;
                const float bsv = bias[pi];
                const float sc  = gam[pi]*rsqrtf(var[pi]+EPSBN);
                const float sh  = bet[pi] - mu[pi]*sc;
                float yv[32];
                #pragma unroll
                for (int i = 0; i < 16; ++i) {
                    const unsigned int w2 = *reinterpret_cast<const unsigned int*>(
                        &Ytb[ch*134 + sIdx*32 + i*2]);
                    yv[2*i]   = bf2f((unsigned short)(w2 & 0xffffu)) + bsv;
                    yv[2*i+1] = bf2f((unsigned short)(w2 >> 16)) + bsv;
                }
                unsigned short* op = og + ((size_t)(b*16)*53 + s)*1600 + g*200 + ch;
                if (p == 0) {
                    #pragma unroll
                    for (int tq = 0; tq < 16; ++tq) {
                        const float r = fmaxf(fmaxf(fmaf(yv[2*tq],sc,sh), fmaf(yv[2*tq+1],sc,sh)), 0.f);
                        op[(size_t)tq*84800] = f2bf(r);
                    }
                } else if (p == 1) {
                    const float w0_ = k3[(g*40+n)*3+0], w1_ = k3[(g*40+n)*3+1], w2_ = k3[(g*40+n)*3+2];
                    #pragma unroll
                    for (int tq = 0; tq < 16; ++tq) {
                        float a = yv[2*tq]*w1_;
                        if (tq > 0) a = fmaf(yv[2*tq-1], w0_, a);
                        a = fmaf(yv[2*tq+1], w2_, a);
                        float c2 = fmaf(yv[2*tq], w0_, yv[2*tq+1]*w1_);
                        if (tq < 15) c2 = fmaf(yv[2*tq+2], w2_, c2);
                        const float r = fmaxf(fmaxf(fmaf(a,sc,sh), fmaf(c2,sc,sh)), 0.f);
                        op[(size_t)tq*84800] = f2bf(r);
                    }
                } else if (p == 2) {
                    float wk[5];
                    #pragma unroll
                    for (int j = 0; j < 5; ++j) wk[j] = k5[(g*40+n)*5+j];
                    #pragma unroll
                    for (int tq = 0; tq < 16; ++tq) {
                        float vv[2];
                        #pragma unroll
                        for (int q = 0; q < 2; ++q) {
                            const int t = 2*tq + q;
                            float v = 0.f;
                            #pragma unroll
                            for (int j = 0; j < 5; ++j) {
                                const int ttp = t + j - 2;
                                if (ttp >= 0 && ttp < 32) v = fmaf(yv[ttp], wk[j], v);
                            }
                            vv[q] = v;
                        }
                        const float r = fmaxf(fmaxf(fmaf(vv[0],sc,sh), fmaf(vv[1],sc,sh)), 0.f);
                        op[(size_t)tq*84800] = f2bf(r);
                    }
                } else if (p == 3) {
                    float wk[7];
                    #pragma unroll
                    for (int j = 0; j < 7; ++j) wk[j] = k7[(g*40+n)*7+j];
                    #pragma unroll
                    for (int tq = 0; tq < 16; ++tq) {
                        float vv[2];
                        #pragma unroll
                        for (int q = 0; q < 2; ++q) {
                            const int t = 2*tq + q;
                            float v = 0.f;
                            #pragma unroll
                            for (int j = 0; j < 7; ++j) {
                                const int ttp = t + j - 3;
                                if (ttp >= 0 && ttp < 32) v = fmaf(yv[ttp], wk[j], v);
                            }
                            vv[q] = v;
                        }
                        const float r = fmaxf(fmaxf(fmaf(vv[0],sc,sh), fmaf(vv[1],sc,sh)), 0.f);
                        op[(size_t)tq*84800] = f2bf(r);
                    }
                } else {
                    #pragma unroll
                    for (int tq = 0; tq < 16; ++tq) {
                        const float v0 = fmaxf(yv[2*tq], yv[2*tq+1]);
                        const float v1 = fmaxf(yv[2*tq+1], yv[(2*tq+2 < 32) ? 2*tq+2 : 31]);
                        const float r = fmaxf(fmaxf(fmaf(v0,sc,sh), fmaf(v1,sc,sh)), 0.f);
                        op[(size_t)tq*84800] = f2bf(r);
                    }
                }
            }
        }
    }
}

// ---------------------------------------------------------------------------
// Shuffle: read og bf16 group-major (g*200+pq) -> write f32 ref order pq*8+g
// ---------------------------------------------------------------------------
__global__ __launch_bounds__(256) void tc_shuffle(const unsigned short* __restrict__ og,
                                                  float* __restrict__ o) {
    __shared__ unsigned short row[1600];
    const size_t base = (size_t)blockIdx.x * 1600;
    const int tid = threadIdx.x;
    if (tid < 200)
        *reinterpret_cast<ushort8*>(&row[tid*8]) =
            *reinterpret_cast<const ushort8*>(&og[base + (size_t)tid*8]);
    __syncthreads();
    #pragma unroll
    for (int it = 0; it < 2; ++it) {
        const int f4 = tid + it*256;
        if (f4 < 400) {
            const int c = f4*4;
            float4 v;
            v.x = bf2f(row[((c  ) & 7)*200 + ((c  ) >> 3)]);
            v.y = bf2f(row[((c+1) & 7)*200 + ((c+1) >> 3)]);
            v.z = bf2f(row[((c+2) & 7)*200 + ((c+2) >> 3)]);
            v.w = bf2f(row[((c+3) & 7)*200 + ((c+3) >> 3)]);
            *reinterpret_cast<float4*>(&o[base + (size_t)c]) = v;
        }
    }
}

extern "C" void kernel_launch(void* const* d_in, const int* in_sizes, int n_in,
                              void* d_out, int out_size, void* d_ws, size_t ws_size,
                              hipStream_t stream) {
    const float* x    = (const float*)d_in[0];
    const float* w0   = (const float*)d_in[1];
    const float* b0   = (const float*)d_in[2];
    const float* k3_0 = (const float*)d_in[3];
    const float* k5_0 = (const float*)d_in[4];
    const float* k7_0 = (const float*)d_in[5];
    const float* g0   = (const float*)d_in[6];
    const float* be0  = (const float*)d_in[7];
    const float* mu0  = (const float*)d_in[8];
    const float* v0   = (const float*)d_in[9];
    const float* w1   = (const float*)d_in[10];
    const float* b1   = (const float*)d_in[11];
    const float* k3_1 = (const float*)d_in[12];
    const float* k5_1 = (const float*)d_in[13];
    const float* k7_1 = (const float*)d_in[14];
    const float* g1   = (const float*)d_in[15];
    const float* be1  = (const float*)d_in[16];
    const float* mu1  = (const float*)d_in[17];
    const float* v1   = (const float*)d_in[18];

    // workspace layout (u16 units) -- total ~118 MB
    const size_t n_zb   = 34734080;     // 16*32*53*1280
    const size_t n_W0t  = 163840;       // 8*160*128
    const size_t n_W1t  = 256000;       // 8*200*160
    const size_t n_extb = 2097152;      // 16*2*64*1024

    unsigned short* zb   = (unsigned short*)d_ws;
    unsigned short* W0t  = zb + n_zb;
    unsigned short* W1t  = W0t + n_W0t;
    unsigned short* extb = W1t + n_W1t;
    unsigned short* og   = extb + n_extb;

    tc_prep_reduce0<<<1024 + 1640, 256, 0, stream>>>(x, extb, w0, w1, W0t, W1t);
    tc_layer0 <<<416*8, 512, 0, stream>>>(x, extb, W0t, b0, k3_0, k5_0,
                                          k7_0, g0, be0, mu0, v0, zb);
    tc_reduce1<<<16*32, 320, 0, stream>>>(zb);
    tc_layer1 <<<224*8, 512, 0, stream>>>(zb, W1t, b1, k3_1, k5_1, k7_1,
                                          g1, be1, mu1, v1, og);
    tc_shuffle<<<16*16*53, 256, 0, stream>>>(og, (float*)d_out);
}

// Round 10
// 251.929 us; speedup vs baseline: 2.0986x; 2.0986x over previous
//
#include <hip/hip_runtime.h>
#include <hip/hip_bf16.h>

#define EPSBN 1e-3f

typedef __attribute__((ext_vector_type(8))) short bf16x8;
typedef __attribute__((ext_vector_type(8))) unsigned short ushort8;
typedef __attribute__((ext_vector_type(4))) float f32x4;

// ---------------------------------------------------------------------------
//   x    : (16, 64, 49, 1024) f32
//   extb : (16, 2, 64, 1024)  bf16   [slot 0: max over s, slot 1: mean]
//   zb2  : (16, 32, 53, 1280) bf16   GROUP-MAJOR ch = g0*160 + (p*32+n);
//                                    s<51 by layer0, s=51,52 by reduce1
//   W0t  : bf16 [8 g][160 n][128 k]
//   W1t  : bf16 [8 g][200 n][160 k-permuted] (kref = (k%20)*8 + k/20)
//   og   : (16, 16, 53, 1600) bf16   group-major layer1 output
//   out  : (16, 16, 53, 1600) f32    ref channel order (pq*8+g), by tc_shuffle
// ---------------------------------------------------------------------------

__device__ __forceinline__ float bf2f(unsigned short u) {
    union { unsigned int i; float f; } c; c.i = (unsigned int)u << 16; return c.f;
}
__device__ __forceinline__ unsigned short f2bf(float f) {
    union { float f; unsigned int i; } c; c.f = f;
    unsigned int r = c.i + 0x7FFF + ((c.i >> 16) & 1);   // RNE
    return (unsigned short)(r >> 16);
}

// ---------------------------------------------------------------------------
// Combined: blocks 0..1023 = reduce0 (max/mean over s -> extb);
//           blocks 1024..2663 = weight transpose prep.
// ---------------------------------------------------------------------------
__global__ __launch_bounds__(256) void tc_prep_reduce0(
    const float* __restrict__ x, unsigned short* __restrict__ extb,
    const float* __restrict__ w0, const float* __restrict__ w1,
    unsigned short* __restrict__ W0t, unsigned short* __restrict__ W1t)
{
    if (blockIdx.x < 1024) {
        const int bt = blockIdx.x;              // b*64+t
        const int b  = bt >> 6, t = bt & 63;
        const int c  = threadIdx.x * 4;
        const float4* src = reinterpret_cast<const float4*>(x + (size_t)bt * 49 * 1024 + c);
        float4 v = src[0];
        float mx0 = v.x, mx1 = v.y, mx2 = v.z, mx3 = v.w;
        float sm0 = v.x, sm1 = v.y, sm2 = v.z, sm3 = v.w;
        for (int s = 1; s < 49; ++s) {
            float4 u = src[(size_t)s * 256];
            mx0 = fmaxf(mx0, u.x); sm0 += u.x;
            mx1 = fmaxf(mx1, u.y); sm1 += u.y;
            mx2 = fmaxf(mx2, u.z); sm2 += u.z;
            mx3 = fmaxf(mx3, u.w); sm3 += u.w;
        }
        const float inv = 1.0f / 49.0f;
        ushort4 omx, omn;
        omx.x=f2bf(mx0); omx.y=f2bf(mx1); omx.z=f2bf(mx2); omx.w=f2bf(mx3);
        omn.x=f2bf(sm0*inv); omn.y=f2bf(sm1*inv); omn.z=f2bf(sm2*inv); omn.w=f2bf(sm3*inv);
        *reinterpret_cast<ushort4*>(&extb[((size_t)(b*2 + 0)*64 + t)*1024 + c]) = omx;
        *reinterpret_cast<ushort4*>(&extb[((size_t)(b*2 + 1)*64 + t)*1024 + c]) = omn;
    } else {
        const int idx = (blockIdx.x - 1024) * 256 + threadIdx.x;
        if (idx < 163840) {                         // 8*160*128
            const int g   = idx / 20480;
            const int rem = idx - g*20480;
            const int n   = rem >> 7;
            const int k   = rem & 127;
            const int p   = n >> 5, nn = n & 31;
            W0t[idx] = f2bf(w0[(((size_t)p*8 + g)*128 + k)*32 + nn]);
        } else if (idx < 163840 + 256000) {         // 8*200*160
            const int i2  = idx - 163840;
            const int g   = i2 / 32000;
            const int rem = i2 - g*32000;
            const int n   = rem / 160;
            const int k   = rem - n*160;
            const int kref = (k % 20)*8 + k/20;
            const int p   = n / 40, nn = n - p*40;
            W1t[i2] = f2bf(w1[(((size_t)p*8 + g)*160 + kref)*40 + nn]);
        }
    }
}

// ---------------------------------------------------------------------------
// Layer 0: block (b, s-pair, g).  M = 128 rows = 2 s-columns x 64 t.
// 8 waves (512 thr); A staged f32->bf16 from x (ext columns from extb).
// Yt overlay stride 134 u16 (67 dw, odd) -> conflict-free epilogue reads.
// ---------------------------------------------------------------------------
__global__ __launch_bounds__(512, 4) void tc_layer0(
    const float* __restrict__ x, const unsigned short* __restrict__ extb,
    const unsigned short* __restrict__ W0t, const float* __restrict__ bias,
    const float* __restrict__ k3, const float* __restrict__ k5,
    const float* __restrict__ k7,
    const float* __restrict__ gam, const float* __restrict__ bet,
    const float* __restrict__ mu, const float* __restrict__ var,
    unsigned short* __restrict__ zb)
{
    const int tid = threadIdx.x;
    const int g   = blockIdx.x / 416;       // 416 = 16 b * 26 s-pairs; 416%8==0
    const int rem = blockIdx.x % 416;
    const int sp  = rem % 26;
    const int b   = rem / 26;
    const int s0  = sp*2;
    const int has1 = (s0 + 1 < 51);

    __shared__ __align__(16) unsigned short lds[128*136 + 160*40];  // 23808 u16 = 47.6KB
    unsigned short* AtU = lds;              // [128][136] bf16 (rows 0-63: s0, 64-127: s1)
    unsigned short* WtU = lds + 128*136;    // [160][40] bf16 (32-k chunk)
    unsigned short* Ytb = lds;              // [160][134] bf16 overlay (21440 u16)

    // ---- stage At (128 rows x 128 k) f32 -> bf16 (ext rows from extb) ----
    #pragma unroll
    for (int it = 0; it < 4; ++it) {
        const int fid = tid + it*512;           // < 2048
        const int row = fid >> 4;
        const int ch8 = (fid & 15) * 8;
        const int t   = row & 63;
        const int s   = (row < 64) ? s0 : (has1 ? s0+1 : s0);
        ushort8 u;
        if (s < 49) {
            const float* sp_ = x + ((size_t)(b*64 + t)*49 + s)*1024 + g*128 + ch8;
            const float4 f0 = *reinterpret_cast<const float4*>(sp_);
            const float4 f1 = *reinterpret_cast<const float4*>(sp_ + 4);
            u[0]=f2bf(f0.x); u[1]=f2bf(f0.y); u[2]=f2bf(f0.z); u[3]=f2bf(f0.w);
            u[4]=f2bf(f1.x); u[5]=f2bf(f1.y); u[6]=f2bf(f1.z); u[7]=f2bf(f1.w);
        } else {
            u = *reinterpret_cast<const ushort8*>(
                &extb[((size_t)(b*2 + (s-49))*64 + t)*1024 + g*128 + ch8]);
        }
        *reinterpret_cast<ushort8*>(&AtU[row*136 + ch8]) = u;
    }

    const int lane = tid & 63;
    const int wid  = tid >> 6;              // t-tile 0..7 over M=128
    const int fr   = lane & 15;
    const int kb   = lane >> 4;

    f32x4 zero = {0.f, 0.f, 0.f, 0.f};
    f32x4 acc[10];
    #pragma unroll
    for (int i = 0; i < 10; ++i) acc[i] = zero;

    for (int kc = 0; kc < 4; ++kc) {
        __syncthreads();
        #pragma unroll
        for (int it = 0; it < 2; ++it) {        // stage 160 n x 32 k
            const int gi = tid + it*512;        // < 640
            if (gi < 640) {
                const int n = gi >> 2, part = (gi & 3) * 8;
                *reinterpret_cast<ushort8*>(&WtU[n*40 + part]) =
                    *reinterpret_cast<const ushort8*>(
                        &W0t[((size_t)g*160 + n)*128 + kc*32 + part]);
            }
        }
        __syncthreads();
        const bf16x8 bfrag = *reinterpret_cast<const bf16x8*>(
            &AtU[(wid*16 + fr)*136 + kc*32 + kb*8]);
        #pragma unroll
        for (int nt = 0; nt < 10; ++nt) {
            const bf16x8 afrag = *reinterpret_cast<const bf16x8*>(
                &WtU[(nt*16 + fr)*40 + kb*8]);
            acc[nt] = __builtin_amdgcn_mfma_f32_16x16x32_bf16(afrag, bfrag, acc[nt], 0, 0, 0);
        }
    }
    __syncthreads();
    // D: row(n) = nt*16 + kb*4 + r, col = wid*16 + fr  (cols 0-63: s0, 64-127: s1)
    #pragma unroll
    for (int nt = 0; nt < 10; ++nt)
        #pragma unroll
        for (int r = 0; r < 4; ++r)
            Ytb[(nt*16 + kb*4 + r)*134 + wid*16 + fr] = f2bf(acc[nt][r]);
    __syncthreads();

    // ---- epilogue: 320 tasks = 160 ch x 2 s ----
    if (tid < 320) {
        const int sIdx = (tid >= 160) ? 1 : 0;
        const int ch   = tid - sIdx*160;
        if (!sIdx || has1) {
            const int s  = s0 + sIdx;
            const int p  = ch >> 5, n = ch & 31;
            const int pi = (p*8 + g)*32 + n;
            const float bsv = bias[pi];
            const float sc  = gam[pi]*rsqrtf(var[pi]+EPSBN);
            const float sh  = bet[pi] - mu[pi]*sc;
            float yv[64];
            #pragma unroll
            for (int i = 0; i < 32; ++i) {
                const unsigned int w2 = *reinterpret_cast<const unsigned int*>(
                    &Ytb[ch*134 + sIdx*64 + i*2]);
                yv[2*i]   = bf2f((unsigned short)(w2 & 0xffffu)) + bsv;
                yv[2*i+1] = bf2f((unsigned short)(w2 >> 16)) + bsv;
            }
            unsigned short* zp = zb + ((size_t)(b*32)*53 + s)*1280 + g*160 + ch;
            if (p == 0) {
                #pragma unroll
                for (int tq = 0; tq < 32; ++tq) {
                    const float r = fmaxf(fmaxf(fmaf(yv[2*tq],sc,sh), fmaf(yv[2*tq+1],sc,sh)), 0.f);
                    zp[(size_t)tq*67840] = f2bf(r);
                }
            } else if (p == 1) {
                const float w0_ = k3[(g*32+n)*3+0], w1_ = k3[(g*32+n)*3+1], w2_ = k3[(g*32+n)*3+2];
                #pragma unroll
                for (int tq = 0; tq < 32; ++tq) {
                    float a = yv[2*tq]*w1_;
                    if (tq > 0) a = fmaf(yv[2*tq-1], w0_, a);
                    a = fmaf(yv[2*tq+1], w2_, a);
                    float c2 = fmaf(yv[2*tq], w0_, yv[2*tq+1]*w1_);
                    if (tq < 31) c2 = fmaf(yv[2*tq+2], w2_, c2);
                    const float r = fmaxf(fmaxf(fmaf(a,sc,sh), fmaf(c2,sc,sh)), 0.f);
                    zp[(size_t)tq*67840] = f2bf(r);
                }
            } else if (p == 2) {
                float wk[5];
                #pragma unroll
                for (int j = 0; j < 5; ++j) wk[j] = k5[(g*32+n)*5+j];
                #pragma unroll
                for (int tq = 0; tq < 32; ++tq) {
                    float vv[2];
                    #pragma unroll
                    for (int q = 0; q < 2; ++q) {
                        const int t = 2*tq + q;
                        float v = 0.f;
                        #pragma unroll
                        for (int j = 0; j < 5; ++j) {
                            const int ttp = t + j - 2;
                            if (ttp >= 0 && ttp < 64) v = fmaf(yv[ttp], wk[j], v);
                        }
                        vv[q] = v;
                    }
                    const float r = fmaxf(fmaxf(fmaf(vv[0],sc,sh), fmaf(vv[1],sc,sh)), 0.f);
                    zp[(size_t)tq*67840] = f2bf(r);
                }
            } else if (p == 3) {
                float wk[7];
                #pragma unroll
                for (int j = 0; j < 7; ++j) wk[j] = k7[(g*32+n)*7+j];
                #pragma unroll
                for (int tq = 0; tq < 32; ++tq) {
                    float vv[2];
                    #pragma unroll
                    for (int q = 0; q < 2; ++q) {
                        const int t = 2*tq + q;
                        float v = 0.f;
                        #pragma unroll
                        for (int j = 0; j < 7; ++j) {
                            const int ttp = t + j - 3;
                            if (ttp >= 0 && ttp < 64) v = fmaf(yv[ttp], wk[j], v);
                        }
                        vv[q] = v;
                    }
                    const float r = fmaxf(fmaxf(fmaf(vv[0],sc,sh), fmaf(vv[1],sc,sh)), 0.f);
                    zp[(size_t)tq*67840] = f2bf(r);
                }
            } else {
                #pragma unroll
                for (int tq = 0; tq < 32; ++tq) {
                    const float v0 = fmaxf(yv[2*tq], yv[2*tq+1]);
                    const float v1 = fmaxf(yv[2*tq+1], yv[(2*tq+2 < 64) ? 2*tq+2 : 63]);
                    const float r = fmaxf(fmaxf(fmaf(v0,sc,sh), fmaf(v1,sc,sh)), 0.f);
                    zp[(size_t)tq*67840] = f2bf(r);
                }
            }
        }
    }
}

// ---------------------------------------------------------------------------
// reduce1: fills zb2 columns s=51 (max) and s=52 (mean) per (b,tq) row.
// ---------------------------------------------------------------------------
__global__ __launch_bounds__(320) void tc_reduce1(unsigned short* __restrict__ zb) {
    const int bt = blockIdx.x;              // b*32+tq
    const int c  = threadIdx.x * 4;         // 0..1276
    unsigned short* base = zb + (size_t)bt * 67840;
    ushort4 u = *reinterpret_cast<const ushort4*>(&base[c]);
    float v0 = bf2f(u.x), v1 = bf2f(u.y), v2 = bf2f(u.z), v3 = bf2f(u.w);
    float mx0 = v0, mx1 = v1, mx2 = v2, mx3 = v3;
    float sm0 = v0, sm1 = v1, sm2 = v2, sm3 = v3;
    for (int s = 1; s < 51; ++s) {
        ushort4 w = *reinterpret_cast<const ushort4*>(&base[(size_t)s*1280 + c]);
        v0 = bf2f(w.x); v1 = bf2f(w.y); v2 = bf2f(w.z); v3 = bf2f(w.w);
        mx0 = fmaxf(mx0, v0); sm0 += v0;
        mx1 = fmaxf(mx1, v1); sm1 += v1;
        mx2 = fmaxf(mx2, v2); sm2 += v2;
        mx3 = fmaxf(mx3, v3); sm3 += v3;
    }
    const float inv = 1.0f / 51.0f;
    ushort4 o;
    o.x = f2bf(mx0); o.y = f2bf(mx1); o.z = f2bf(mx2); o.w = f2bf(mx3);
    *reinterpret_cast<ushort4*>(&base[(size_t)51*1280 + c]) = o;
    o.x = f2bf(sm0*inv); o.y = f2bf(sm1*inv); o.z = f2bf(sm2*inv); o.w = f2bf(sm3*inv);
    *reinterpret_cast<ushort4*>(&base[(size_t)52*1280 + c]) = o;
}

// ---------------------------------------------------------------------------
// Layer 1: block (b, s-quad, g).  M = 128 rows = 4 s-columns x 32 t.
// ---------------------------------------------------------------------------
__global__ __launch_bounds__(512, 4) void tc_layer1(
    const unsigned short* __restrict__ zbi,
    const unsigned short* __restrict__ W1t, const float* __restrict__ bias,
    const float* __restrict__ k3, const float* __restrict__ k5,
    const float* __restrict__ k7,
    const float* __restrict__ gam, const float* __restrict__ bet,
    const float* __restrict__ mu, const float* __restrict__ var,
    unsigned short* __restrict__ og)
{
    const int tid = threadIdx.x;
    const int g   = blockIdx.x / 224;       // 224 = 16 b * 14 s-quads; 224%8==0
    const int rem = blockIdx.x % 224;
    const int sq  = rem % 14;
    const int b   = rem / 14;
    const int s0  = sq*4;
    const int ns  = (53 - s0 < 4) ? (53 - s0) : 4;

    __shared__ __align__(16) unsigned short lds[128*168 + 208*40];  // 29824 u16 = 58.3 KB
    unsigned short* AtU = lds;              // [128][168] bf16 (rows: sLocal*32 + t)
    unsigned short* WtU = lds + 128*168;    // [208][40] bf16 (rows 200-207 zero)
    unsigned short* Ytb = lds;              // [200][134] bf16 overlay (26800 u16)

    if (tid < 40) {
        ushort8 z8 = {0,0,0,0,0,0,0,0};
        const int r = tid / 5, cp = tid - r*5;
        *reinterpret_cast<ushort8*>(&WtU[(200 + r)*40 + cp*8]) = z8;
    }

    // ---- gather At (128 rows x 160 k, z0g k-order) ----
    #pragma unroll
    for (int it = 0; it < 10; ++it) {
        const int fid = tid + it*512;           // < 5120
        const int row = fid / 40;
        const int seg = fid - row*40;
        const int gg  = seg / 5, q = seg - gg*5;
        const int ch  = gg*160 + g*20 + q*4;
        const int sl  = row >> 5;
        const int s   = s0 + ((sl < ns) ? sl : 0);
        const int t   = row & 31;
        const unsigned short* src = zbi + ((size_t)(b*32 + t)*53 + s)*1280 + ch;
        *reinterpret_cast<ushort4*>(&AtU[row*168 + seg*4]) =
            *reinterpret_cast<const ushort4*>(src);
    }

    const int lane = tid & 63;
    const int wid  = tid >> 6;              // t-tile 0..7 over M=128
    const int fr   = lane & 15;
    const int kb   = lane >> 4;

    f32x4 zero = {0.f, 0.f, 0.f, 0.f};
    f32x4 acc[13];
    #pragma unroll
    for (int i = 0; i < 13; ++i) acc[i] = zero;

    for (int kc = 0; kc < 5; ++kc) {
        __syncthreads();
        #pragma unroll
        for (int it = 0; it < 2; ++it) {        // stage 200 n x 32 k
            const int gi = tid + it*512;        // < 800
            if (gi < 800) {
                const int n = gi >> 2, part = (gi & 3) * 8;
                *reinterpret_cast<ushort8*>(&WtU[n*40 + part]) =
                    *reinterpret_cast<const ushort8*>(
                        &W1t[((size_t)g*200 + n)*160 + kc*32 + part]);
            }
        }
        __syncthreads();
        const bf16x8 bfrag = *reinterpret_cast<const bf16x8*>(
            &AtU[(wid*16 + fr)*168 + kc*32 + kb*8]);
        #pragma unroll
        for (int nt = 0; nt < 13; ++nt) {
            const bf16x8 afrag = *reinterpret_cast<const bf16x8*>(
                &WtU[(nt*16 + fr)*40 + kb*8]);
            acc[nt] = __builtin_amdgcn_mfma_f32_16x16x32_bf16(afrag, bfrag, acc[nt], 0, 0, 0);
        }
    }
    __syncthreads();
    #pragma unroll
    for (int nt = 0; nt < 13; ++nt) {
        #pragma unroll
        for (int r = 0; r < 4; ++r) {
            const int n = nt*16 + kb*4 + r;
            if (n < 200) Ytb[n*134 + wid*16 + fr] = f2bf(acc[nt][r]);
        }
    }
    __syncthreads();

    // ---- epilogue: 800 tasks = 200 ch x 4 s ----
    #pragma unroll
    for (int it = 0; it < 2; ++it) {
        const int task = tid + it*512;
        if (task < 800) {
            const int sIdx = task / 200;
            const int ch   = task - sIdx*200;
            if (sIdx < ns) {
                const int s  = s0 + sIdx;
                const int p  = ch / 40, n = ch - p*40;
                const int pi = (p*8 + g)*40 + n;
                const float bsv = bias[pi];
                const float sc  = gam[pi]*rsqrtf(var[pi]+EPSBN);
                const float sh  = bet[pi] - mu[pi]*sc;
                float yv[32];
                #pragma unroll
                for (int i = 0; i < 16; ++i) {
                    const unsigned int w2 = *reinterpret_cast<const unsigned int*>(
                        &Ytb[ch*134 + sIdx*32 + i*2]);
                    yv[2*i]   = bf2f((unsigned short)(w2 & 0xffffu)) + bsv;
                    yv[2*i+1] = bf2f((unsigned short)(w2 >> 16)) + bsv;
                }
                unsigned short* op = og + ((size_t)(b*16)*53 + s)*1600 + g*200 + ch;
                if (p == 0) {
                    #pragma unroll
                    for (int tq = 0; tq < 16; ++tq) {
                        const float r = fmaxf(fmaxf(fmaf(yv[2*tq],sc,sh), fmaf(yv[2*tq+1],sc,sh)), 0.f);
                        op[(size_t)tq*84800] = f2bf(r);
                    }
                } else if (p == 1) {
                    const float w0_ = k3[(g*40+n)*3+0], w1_ = k3[(g*40+n)*3+1], w2_ = k3[(g*40+n)*3+2];
                    #pragma unroll
                    for (int tq = 0; tq < 16; ++tq) {
                        float a = yv[2*tq]*w1_;
                        if (tq > 0) a = fmaf(yv[2*tq-1], w0_, a);
                        a = fmaf(yv[2*tq+1], w2_, a);
                        float c2 = fmaf(yv[2*tq], w0_, yv[2*tq+1]*w1_);
                        if (tq < 15) c2 = fmaf(yv[2*tq+2], w2_, c2);
                        const float r = fmaxf(fmaxf(fmaf(a,sc,sh), fmaf(c2,sc,sh)), 0.f);
                        op[(size_t)tq*84800] = f2bf(r);
                    }
                } else if (p == 2) {
                    float wk[5];
                    #pragma unroll
                    for (int j = 0; j < 5; ++j) wk[j] = k5[(g*40+n)*5+j];
                    #pragma unroll
                    for (int tq = 0; tq < 16; ++tq) {
                        float vv[2];
                        #pragma unroll
                        for (int q = 0; q < 2; ++q) {
                            const int t = 2*tq + q;
                            float v = 0.f;
                            #pragma unroll
                            for (int j = 0; j < 5; ++j) {
                                const int ttp = t + j - 2;
                                if (ttp >= 0 && ttp < 32) v = fmaf(yv[ttp], wk[j], v);
                            }
                            vv[q] = v;
                        }
                        const float r = fmaxf(fmaxf(fmaf(vv[0],sc,sh), fmaf(vv[1],sc,sh)), 0.f);
                        op[(size_t)tq*84800] = f2bf(r);
                    }
                } else if (p == 3) {
                    float wk[7];
                    #pragma unroll
                    for (int j = 0; j < 7; ++j) wk[j] = k7[(g*40+n)*7+j];
                    #pragma unroll
                    for (int tq = 0; tq < 16; ++tq) {
                        float vv[2];
                        #pragma unroll
                        for (int q = 0; q < 2; ++q) {
                            const int t = 2*tq + q;
                            float v = 0.f;
                            #pragma unroll
                            for (int j = 0; j < 7; ++j) {
                                const int ttp = t + j - 3;
                                if (ttp >= 0 && ttp < 32) v = fmaf(yv[ttp], wk[j], v);
                            }
                            vv[q] = v;
                        }
                        const float r = fmaxf(fmaxf(fmaf(vv[0],sc,sh), fmaf(vv[1],sc,sh)), 0.f);
                        op[(size_t)tq*84800] = f2bf(r);
                    }
                } else {
                    #pragma unroll
                    for (int tq = 0; tq < 16; ++tq) {
                        const float v0 = fmaxf(yv[2*tq], yv[2*tq+1]);
                        const float v1 = fmaxf(yv[2*tq+1], yv[(2*tq+2 < 32) ? 2*tq+2 : 31]);
                        const float r = fmaxf(fmaxf(fmaf(v0,sc,sh), fmaf(v1,sc,sh)), 0.f);
                        op[(size_t)tq*84800] = f2bf(r);
                    }
                }
            }
        }
    }
}

// ---------------------------------------------------------------------------
// Shuffle: read og bf16 group-major (g*200+pq) -> write f32 ref order pq*8+g
// ---------------------------------------------------------------------------
__global__ __launch_bounds__(256) void tc_shuffle(const unsigned short* __restrict__ og,
                                                  float* __restrict__ o) {
    __shared__ unsigned short row[1600];
    const size_t base = (size_t)blockIdx.x * 1600;
    const int tid = threadIdx.x;
    if (tid < 200)
        *reinterpret_cast<ushort8*>(&row[tid*8]) =
            *reinterpret_cast<const ushort8*>(&og[base + (size_t)tid*8]);
    __syncthreads();
    #pragma unroll
    for (int it = 0; it < 2; ++it) {
        const int f4 = tid + it*256;
        if (f4 < 400) {
            const int c = f4*4;
            float4 v;
            v.x = bf2f(row[((c  ) & 7)*200 + ((c  ) >> 3)]);
            v.y = bf2f(row[((c+1) & 7)*200 + ((c+1) >> 3)]);
            v.z = bf2f(row[((c+2) & 7)*200 + ((c+2) >> 3)]);
            v.w = bf2f(row[((c+3) & 7)*200 + ((c+3) >> 3)]);
            *reinterpret_cast<float4*>(&o[base + (size_t)c]) = v;
        }
    }
}

extern "C" void kernel_launch(void* const* d_in, const int* in_sizes, int n_in,
                              void* d_out, int out_size, void* d_ws, size_t ws_size,
                              hipStream_t stream) {
    const float* x    = (const float*)d_in[0];
    const float* w0   = (const float*)d_in[1];
    const float* b0   = (const float*)d_in[2];
    const float* k3_0 = (const float*)d_in[3];
    const float* k5_0 = (const float*)d_in[4];
    const float* k7_0 = (const float*)d_in[5];
    const float* g0   = (const float*)d_in[6];
    const float* be0  = (const float*)d_in[7];
    const float* mu0  = (const float*)d_in[8];
    const float* v0   = (const float*)d_in[9];
    const float* w1   = (const float*)d_in[10];
    const float* b1   = (const float*)d_in[11];
    const float* k3_1 = (const float*)d_in[12];
    const float* k5_1 = (const float*)d_in[13];
    const float* k7_1 = (const float*)d_in[14];
    const float* g1   = (const float*)d_in[15];
    const float* be1  = (const float*)d_in[16];
    const float* mu1  = (const float*)d_in[17];
    const float* v1   = (const float*)d_in[18];

    // workspace layout (u16 units) -- total ~118 MB
    const size_t n_zb   = 34734080;     // 16*32*53*1280
    const size_t n_W0t  = 163840;       // 8*160*128
    const size_t n_W1t  = 256000;       // 8*200*160
    const size_t n_extb = 2097152;      // 16*2*64*1024

    unsigned short* zb   = (unsigned short*)d_ws;
    unsigned short* W0t  = zb + n_zb;
    unsigned short* W1t  = W0t + n_W0t;
    unsigned short* extb = W1t + n_W1t;
    unsigned short* og   = extb + n_extb;

    tc_prep_reduce0<<<1024 + 1640, 256, 0, stream>>>(x, extb, w0, w1, W0t, W1t);
    tc_layer0 <<<416*8, 512, 0, stream>>>(x, extb, W0t, b0, k3_0, k5_0,
                                          k7_0, g0, be0, mu0, v0, zb);
    tc_reduce1<<<16*32, 320, 0, stream>>>(zb);
    tc_layer1 <<<224*8, 512, 0, stream>>>(zb, W1t, b1, k3_1, k5_1, k7_1,
                                          g1, be1, mu1, v1, og);
    tc_shuffle<<<16*16*53, 256, 0, stream>>>(og, (float*)d_out);
}

// Round 11
// 248.211 us; speedup vs baseline: 2.1300x; 1.0150x over previous
//
#include <hip/hip_runtime.h>
#include <hip/hip_bf16.h>

#define EPSBN 1e-3f

typedef __attribute__((ext_vector_type(8))) short bf16x8;
typedef __attribute__((ext_vector_type(8))) unsigned short ushort8;
typedef __attribute__((ext_vector_type(4))) float f32x4;

// ---------------------------------------------------------------------------
//   x    : (16, 64, 49, 1024) f32
//   extb : (16, 2, 64, 1024)  bf16   [slot 0: max over s, slot 1: mean]
//   zb2  : (16, 32, 53, 1280) bf16   GROUP-MAJOR ch = g0*160 + (p*32+n);
//                                    s<51 by layer0, s=51,52 by reduce1
//   W0t  : bf16 [8 g][160 n][128 k]
//   W1t  : bf16 [8 g][200 n][160 k-permuted] (kref = (k%20)*8 + k/20)
//   og   : (16, 16, 53, 1600) bf16   group-major layer1 output
//   out  : (16, 16, 53, 1600) f32    ref channel order (pq*8+g), by tc_shuffle
// ---------------------------------------------------------------------------

__device__ __forceinline__ float bf2f(unsigned short u) {
    union { unsigned int i; float f; } c; c.i = (unsigned int)u << 16; return c.f;
}
__device__ __forceinline__ unsigned short f2bf(float f) {
    union { float f; unsigned int i; } c; c.f = f;
    unsigned int r = c.i + 0x7FFF + ((c.i >> 16) & 1);   // RNE
    return (unsigned short)(r >> 16);
}

// ---------------------------------------------------------------------------
// Combined: blocks 0..1023 = reduce0 (max/mean over s -> extb);
//           blocks 1024..2663 = weight transpose prep.
// ---------------------------------------------------------------------------
__global__ __launch_bounds__(256) void tc_prep_reduce0(
    const float* __restrict__ x, unsigned short* __restrict__ extb,
    const float* __restrict__ w0, const float* __restrict__ w1,
    unsigned short* __restrict__ W0t, unsigned short* __restrict__ W1t)
{
    if (blockIdx.x < 1024) {
        const int bt = blockIdx.x;              // b*64+t
        const int b  = bt >> 6, t = bt & 63;
        const int c  = threadIdx.x * 4;
        const float4* src = reinterpret_cast<const float4*>(x + (size_t)bt * 49 * 1024 + c);
        float4 v = src[0];
        float mx0 = v.x, mx1 = v.y, mx2 = v.z, mx3 = v.w;
        float sm0 = v.x, sm1 = v.y, sm2 = v.z, sm3 = v.w;
        for (int s = 1; s < 49; ++s) {
            float4 u = src[(size_t)s * 256];
            mx0 = fmaxf(mx0, u.x); sm0 += u.x;
            mx1 = fmaxf(mx1, u.y); sm1 += u.y;
            mx2 = fmaxf(mx2, u.z); sm2 += u.z;
            mx3 = fmaxf(mx3, u.w); sm3 += u.w;
        }
        const float inv = 1.0f / 49.0f;
        ushort4 omx, omn;
        omx.x=f2bf(mx0); omx.y=f2bf(mx1); omx.z=f2bf(mx2); omx.w=f2bf(mx3);
        omn.x=f2bf(sm0*inv); omn.y=f2bf(sm1*inv); omn.z=f2bf(sm2*inv); omn.w=f2bf(sm3*inv);
        *reinterpret_cast<ushort4*>(&extb[((size_t)(b*2 + 0)*64 + t)*1024 + c]) = omx;
        *reinterpret_cast<ushort4*>(&extb[((size_t)(b*2 + 1)*64 + t)*1024 + c]) = omn;
    } else {
        const int idx = (blockIdx.x - 1024) * 256 + threadIdx.x;
        if (idx < 163840) {                         // 8*160*128
            const int g   = idx / 20480;
            const int rem = idx - g*20480;
            const int n   = rem >> 7;
            const int k   = rem & 127;
            const int p   = n >> 5, nn = n & 31;
            W0t[idx] = f2bf(w0[(((size_t)p*8 + g)*128 + k)*32 + nn]);
        } else if (idx < 163840 + 256000) {         // 8*200*160
            const int i2  = idx - 163840;
            const int g   = i2 / 32000;
            const int rem = i2 - g*32000;
            const int n   = rem / 160;
            const int k   = rem - n*160;
            const int kref = (k % 20)*8 + k/20;
            const int p   = n / 40, nn = n - p*40;
            W1t[i2] = f2bf(w1[(((size_t)p*8 + g)*160 + kref)*40 + nn]);
        }
    }
}

// ---------------------------------------------------------------------------
// Layer 0: block (b, s-pair, g).  M = 128 rows = 2 s-columns x 64 t.
// 8 waves (512 thr); A staged f32->bf16 from x (ext columns from extb).
// Yt overlay stride 134 u16 (67 dw, odd) -> conflict-free epilogue reads.
// ---------------------------------------------------------------------------
__global__ __launch_bounds__(512, 4) void tc_layer0(
    const float* __restrict__ x, const unsigned short* __restrict__ extb,
    const unsigned short* __restrict__ W0t, const float* __restrict__ bias,
    const float* __restrict__ k3, const float* __restrict__ k5,
    const float* __restrict__ k7,
    const float* __restrict__ gam, const float* __restrict__ bet,
    const float* __restrict__ mu, const float* __restrict__ var,
    unsigned short* __restrict__ zb)
{
    const int tid = threadIdx.x;
    const int g   = blockIdx.x / 416;       // 416 = 16 b * 26 s-pairs; 416%8==0
    const int rem = blockIdx.x % 416;
    const int sp  = rem % 26;
    const int b   = rem / 26;
    const int s0  = sp*2;
    const int has1 = (s0 + 1 < 51);

    __shared__ __align__(16) unsigned short lds[128*136 + 160*40];  // 23808 u16 = 46.5KB
    unsigned short* AtU = lds;              // [128][136] bf16 (rows 0-63: s0, 64-127: s1)
    unsigned short* WtU = lds + 128*136;    // [160][40] bf16 (32-k chunk)
    unsigned short* Ytb = lds;              // [160][134] bf16 overlay (21440 u16)

    // ---- stage At (128 rows x 128 k) f32 -> bf16 (ext rows from extb) ----
    #pragma unroll
    for (int it = 0; it < 4; ++it) {
        const int fid = tid + it*512;           // < 2048
        const int row = fid >> 4;
        const int ch8 = (fid & 15) * 8;
        const int t   = row & 63;
        const int s   = (row < 64) ? s0 : (has1 ? s0+1 : s0);
        ushort8 u;
        if (s < 49) {
            const float* sp_ = x + ((size_t)(b*64 + t)*49 + s)*1024 + g*128 + ch8;
            const float4 f0 = *reinterpret_cast<const float4*>(sp_);
            const float4 f1 = *reinterpret_cast<const float4*>(sp_ + 4);
            u[0]=f2bf(f0.x); u[1]=f2bf(f0.y); u[2]=f2bf(f0.z); u[3]=f2bf(f0.w);
            u[4]=f2bf(f1.x); u[5]=f2bf(f1.y); u[6]=f2bf(f1.z); u[7]=f2bf(f1.w);
        } else {
            u = *reinterpret_cast<const ushort8*>(
                &extb[((size_t)(b*2 + (s-49))*64 + t)*1024 + g*128 + ch8]);
        }
        *reinterpret_cast<ushort8*>(&AtU[row*136 + ch8]) = u;
    }

    const int lane = tid & 63;
    const int wid  = tid >> 6;              // t-tile 0..7 over M=128
    const int fr   = lane & 15;
    const int kb   = lane >> 4;

    f32x4 zero = {0.f, 0.f, 0.f, 0.f};
    f32x4 acc[10];
    #pragma unroll
    for (int i = 0; i < 10; ++i) acc[i] = zero;

    for (int kc = 0; kc < 4; ++kc) {
        __syncthreads();
        #pragma unroll
        for (int it = 0; it < 2; ++it) {        // stage 160 n x 32 k
            const int gi = tid + it*512;        // < 640
            if (gi < 640) {
                const int n = gi >> 2, part = (gi & 3) * 8;
                *reinterpret_cast<ushort8*>(&WtU[n*40 + part]) =
                    *reinterpret_cast<const ushort8*>(
                        &W0t[((size_t)g*160 + n)*128 + kc*32 + part]);
            }
        }
        __syncthreads();
        const bf16x8 bfrag = *reinterpret_cast<const bf16x8*>(
            &AtU[(wid*16 + fr)*136 + kc*32 + kb*8]);
        #pragma unroll
        for (int nt = 0; nt < 10; ++nt) {
            const bf16x8 afrag = *reinterpret_cast<const bf16x8*>(
                &WtU[(nt*16 + fr)*40 + kb*8]);
            acc[nt] = __builtin_amdgcn_mfma_f32_16x16x32_bf16(afrag, bfrag, acc[nt], 0, 0, 0);
        }
    }
    __syncthreads();
    // D: row(n) = nt*16 + kb*4 + r, col = wid*16 + fr  (cols 0-63: s0, 64-127: s1)
    #pragma unroll
    for (int nt = 0; nt < 10; ++nt)
        #pragma unroll
        for (int r = 0; r < 4; ++r)
            Ytb[(nt*16 + kb*4 + r)*134 + wid*16 + fr] = f2bf(acc[nt][r]);
    __syncthreads();

    // ---- epilogue: 320 tasks = 160 ch x 2 s ----
    if (tid < 320) {
        const int sIdx = (tid >= 160) ? 1 : 0;
        const int ch   = tid - sIdx*160;
        if (!sIdx || has1) {
            const int s  = s0 + sIdx;
            const int p  = ch >> 5, n = ch & 31;
            const int pi = (p*8 + g)*32 + n;
            const float bsv = bias[pi];
            const float sc  = gam[pi]*rsqrtf(var[pi]+EPSBN);
            const float sh  = bet[pi] - mu[pi]*sc;
            float yv[64];
            #pragma unroll
            for (int i = 0; i < 32; ++i) {
                const unsigned int w2 = *reinterpret_cast<const unsigned int*>(
                    &Ytb[ch*134 + sIdx*64 + i*2]);
                yv[2*i]   = bf2f((unsigned short)(w2 & 0xffffu)) + bsv;
                yv[2*i+1] = bf2f((unsigned short)(w2 >> 16)) + bsv;
            }
            unsigned short* zp = zb + ((size_t)(b*32)*53 + s)*1280 + g*160 + ch;
            if (p == 0) {
                #pragma unroll
                for (int tq = 0; tq < 32; ++tq) {
                    const float r = fmaxf(fmaxf(fmaf(yv[2*tq],sc,sh), fmaf(yv[2*tq+1],sc,sh)), 0.f);
                    zp[(size_t)tq*67840] = f2bf(r);
                }
            } else if (p == 1) {
                const float w0_ = k3[(g*32+n)*3+0], w1_ = k3[(g*32+n)*3+1], w2_ = k3[(g*32+n)*3+2];
                #pragma unroll
                for (int tq = 0; tq < 32; ++tq) {
                    float a = yv[2*tq]*w1_;
                    if (tq > 0) a = fmaf(yv[2*tq-1], w0_, a);
                    a = fmaf(yv[2*tq+1], w2_, a);
                    float c2 = fmaf(yv[2*tq], w0_, yv[2*tq+1]*w1_);
                    if (tq < 31) c2 = fmaf(yv[2*tq+2], w2_, c2);
                    const float r = fmaxf(fmaxf(fmaf(a,sc,sh), fmaf(c2,sc,sh)), 0.f);
                    zp[(size_t)tq*67840] = f2bf(r);
                }
            } else if (p == 2) {
                float wk[5];
                #pragma unroll
                for (int j = 0; j < 5; ++j) wk[j] = k5[(g*32+n)*5+j];
                #pragma unroll
                for (int tq = 0; tq < 32; ++tq) {
                    float vv[2];
                    #pragma unroll
                    for (int q = 0; q < 2; ++q) {
                        const int t = 2*tq + q;
                        float v = 0.f;
                        #pragma unroll
                        for (int j = 0; j < 5; ++j) {
                            const int ttp = t + j - 2;
                            if (ttp >= 0 && ttp < 64) v = fmaf(yv[ttp], wk[j], v);
                        }
                        vv[q] = v;
                    }
                    const float r = fmaxf(fmaxf(fmaf(vv[0],sc,sh), fmaf(vv[1],sc,sh)), 0.f);
                    zp[(size_t)tq*67840] = f2bf(r);
                }
            } else if (p == 3) {
                float wk[7];
                #pragma unroll
                for (int j = 0; j < 7; ++j) wk[j] = k7[(g*32+n)*7+j];
                #pragma unroll
                for (int tq = 0; tq < 32; ++tq) {
                    float vv[2];
                    #pragma unroll
                    for (int q = 0; q < 2; ++q) {
                        const int t = 2*tq + q;
                        float v = 0.f;
                        #pragma unroll
                        for (int j = 0; j < 7; ++j) {
                            const int ttp = t + j - 3;
                            if (ttp >= 0 && ttp < 64) v = fmaf(yv[ttp], wk[j], v);
                        }
                        vv[q] = v;
                    }
                    const float r = fmaxf(fmaxf(fmaf(vv[0],sc,sh), fmaf(vv[1],sc,sh)), 0.f);
                    zp[(size_t)tq*67840] = f2bf(r);
                }
            } else {
                #pragma unroll
                for (int tq = 0; tq < 32; ++tq) {
                    const float v0 = fmaxf(yv[2*tq], yv[2*tq+1]);
                    const float v1 = fmaxf(yv[2*tq+1], yv[(2*tq+2 < 64) ? 2*tq+2 : 63]);
                    const float r = fmaxf(fmaxf(fmaf(v0,sc,sh), fmaf(v1,sc,sh)), 0.f);
                    zp[(size_t)tq*67840] = f2bf(r);
                }
            }
        }
    }
}

// ---------------------------------------------------------------------------
// reduce1: fills zb2 columns s=51 (max) and s=52 (mean) per (b,tq) row.
// ---------------------------------------------------------------------------
__global__ __launch_bounds__(320) void tc_reduce1(unsigned short* __restrict__ zb) {
    const int bt = blockIdx.x;              // b*32+tq
    const int c  = threadIdx.x * 4;         // 0..1276
    unsigned short* base = zb + (size_t)bt * 67840;
    ushort4 u = *reinterpret_cast<const ushort4*>(&base[c]);
    float v0 = bf2f(u.x), v1 = bf2f(u.y), v2 = bf2f(u.z), v3 = bf2f(u.w);
    float mx0 = v0, mx1 = v1, mx2 = v2, mx3 = v3;
    float sm0 = v0, sm1 = v1, sm2 = v2, sm3 = v3;
    for (int s = 1; s < 51; ++s) {
        ushort4 w = *reinterpret_cast<const ushort4*>(&base[(size_t)s*1280 + c]);
        v0 = bf2f(w.x); v1 = bf2f(w.y); v2 = bf2f(w.z); v3 = bf2f(w.w);
        mx0 = fmaxf(mx0, v0); sm0 += v0;
        mx1 = fmaxf(mx1, v1); sm1 += v1;
        mx2 = fmaxf(mx2, v2); sm2 += v2;
        mx3 = fmaxf(mx3, v3); sm3 += v3;
    }
    const float inv = 1.0f / 51.0f;
    ushort4 o;
    o.x = f2bf(mx0); o.y = f2bf(mx1); o.z = f2bf(mx2); o.w = f2bf(mx3);
    *reinterpret_cast<ushort4*>(&base[(size_t)51*1280 + c]) = o;
    o.x = f2bf(sm0*inv); o.y = f2bf(sm1*inv); o.z = f2bf(sm2*inv); o.w = f2bf(sm3*inv);
    *reinterpret_cast<ushort4*>(&base[(size_t)52*1280 + c]) = o;
}

// ---------------------------------------------------------------------------
// Layer 1: block (b, s-quad, g).  M = 128 rows = 4 s-columns x 32 t.
// LDS diet: At staged in two k-chunks (k0..95 stride 104, then k96..159
// stride 72 reusing the same buffer); Ytb stride 130 (65 dw, odd).
// Total LDS 50.8 KB -> 3 blocks/CU possible when VGPR <= 84.
// ---------------------------------------------------------------------------
__global__ __launch_bounds__(512, 4) void tc_layer1(
    const unsigned short* __restrict__ zbi,
    const unsigned short* __restrict__ W1t, const float* __restrict__ bias,
    const float* __restrict__ k3, const float* __restrict__ k5,
    const float* __restrict__ k7,
    const float* __restrict__ gam, const float* __restrict__ bet,
    const float* __restrict__ mu, const float* __restrict__ var,
    unsigned short* __restrict__ og)
{
    const int tid = threadIdx.x;
    const int g   = blockIdx.x / 224;       // 224 = 16 b * 14 s-quads; 224%8==0
    const int rem = blockIdx.x % 224;
    const int sq  = rem % 14;
    const int b   = rem / 14;
    const int s0  = sq*4;
    const int ns  = (53 - s0 < 4) ? (53 - s0) : 4;

    __shared__ __align__(16) unsigned short lds[26000];     // 50.8 KB
    unsigned short* AhU = lds;              // h1: [128][96] stride 104; h2: [128][64] stride 72
    unsigned short* WtU = lds + 13312;      // [208][40] bf16 (rows 200-207 zero)
    unsigned short* Ytb = lds;              // [200][130] bf16 overlay (26000 u16)

    // zero W pad rows (survive until last MFMA; clobbered only in epilogue)
    if (tid < 40) {
        ushort8 z8 = {0,0,0,0,0,0,0,0};
        const int r = tid / 5, cp = tid - r*5;
        *reinterpret_cast<ushort8*>(&WtU[(200 + r)*40 + cp*8]) = z8;
    }

    // ---- gather At half 1: 128 rows x segs 0..23 (k 0..95) ----
    #pragma unroll
    for (int it = 0; it < 6; ++it) {
        const int fid = tid + it*512;           // < 3072
        const int row = fid / 24;
        const int seg = fid - row*24;           // 0..23
        const int gg  = seg / 5, q = seg - gg*5;
        const int ch  = gg*160 + g*20 + q*4;
        const int sl  = row >> 5;
        const int s   = s0 + ((sl < ns) ? sl : 0);
        const int t   = row & 31;
        const unsigned short* src = zbi + ((size_t)(b*32 + t)*53 + s)*1280 + ch;
        *reinterpret_cast<ushort4*>(&AhU[row*104 + seg*4]) =
            *reinterpret_cast<const ushort4*>(src);
    }

    const int lane = tid & 63;
    const int wid  = tid >> 6;              // t-tile 0..7 over M=128
    const int fr   = lane & 15;
    const int kb   = lane >> 4;

    f32x4 zero = {0.f, 0.f, 0.f, 0.f};
    f32x4 acc[13];
    #pragma unroll
    for (int i = 0; i < 13; ++i) acc[i] = zero;

    for (int kc = 0; kc < 5; ++kc) {
        __syncthreads();
        if (kc == 3) {
            // ---- gather At half 2: 128 rows x segs 24..39 (k 96..159) ----
            // safe: the barrier above drained all kc<=2 ds_reads of AhU h1.
            #pragma unroll
            for (int it = 0; it < 4; ++it) {
                const int fid = tid + it*512;       // < 2048
                const int row = fid >> 4;
                const int s24 = fid & 15;           // seg-24
                const int seg = s24 + 24;
                const int gg  = seg / 5, q = seg - gg*5;
                const int ch  = gg*160 + g*20 + q*4;
                const int sl  = row >> 5;
                const int s   = s0 + ((sl < ns) ? sl : 0);
                const int t   = row & 31;
                const unsigned short* src = zbi + ((size_t)(b*32 + t)*53 + s)*1280 + ch;
                *reinterpret_cast<ushort4*>(&AhU[row*72 + s24*4]) =
                    *reinterpret_cast<const ushort4*>(src);
            }
        }
        #pragma unroll
        for (int it = 0; it < 2; ++it) {        // stage 200 n x 32 k
            const int gi = tid + it*512;        // < 800
            if (gi < 800) {
                const int n = gi >> 2, part = (gi & 3) * 8;
                *reinterpret_cast<ushort8*>(&WtU[n*40 + part]) =
                    *reinterpret_cast<const ushort8*>(
                        &W1t[((size_t)g*200 + n)*160 + kc*32 + part]);
            }
        }
        __syncthreads();
        const bf16x8 bfrag = (kc < 3)
            ? *reinterpret_cast<const bf16x8*>(&AhU[(wid*16 + fr)*104 + kc*32 + kb*8])
            : *reinterpret_cast<const bf16x8*>(&AhU[(wid*16 + fr)*72 + (kc-3)*32 + kb*8]);
        #pragma unroll
        for (int nt = 0; nt < 13; ++nt) {
            const bf16x8 afrag = *reinterpret_cast<const bf16x8*>(
                &WtU[(nt*16 + fr)*40 + kb*8]);
            acc[nt] = __builtin_amdgcn_mfma_f32_16x16x32_bf16(afrag, bfrag, acc[nt], 0, 0, 0);
        }
    }
    __syncthreads();
    #pragma unroll
    for (int nt = 0; nt < 13; ++nt) {
        #pragma unroll
        for (int r = 0; r < 4; ++r) {
            const int n = nt*16 + kb*4 + r;
            if (n < 200) Ytb[n*130 + wid*16 + fr] = f2bf(acc[nt][r]);
        }
    }
    __syncthreads();

    // ---- epilogue: 800 tasks = 200 ch x 4 s ----
    #pragma unroll
    for (int it = 0; it < 2; ++it) {
        const int task = tid + it*512;
        if (task < 800) {
            const int sIdx = task / 200;
            const int ch   = task - sIdx*200;
            if (sIdx < ns) {
                const int s  = s0 + sIdx;
                const int p  = ch / 40, n = ch - p*40;
                const int pi = (p*8 + g)*40 + n;
                const float bsv = bias[pi];
                const float sc  = gam[pi]*rsqrtf(var[pi]+EPSBN);
                const float sh  = bet[pi] - mu[pi]*sc;
                float yv[32];
                #pragma unroll
                for (int i = 0; i < 16; ++i) {
                    const unsigned int w2 = *reinterpret_cast<const unsigned int*>(
                        &Ytb[ch*130 + sIdx*32 + i*2]);
                    yv[2*i]   = bf2f((unsigned short)(w2 & 0xffffu)) + bsv;
                    yv[2*i+1] = bf2f((unsigned short)(w2 >> 16)) + bsv;
                }
                unsigned short* op = og + ((size_t)(b*16)*53 + s)*1600 + g*200 + ch;
                if (p == 0) {
                    #pragma unroll
                    for (int tq = 0; tq < 16; ++tq) {
                        const float r = fmaxf(fmaxf(fmaf(yv[2*tq],sc,sh), fmaf(yv[2*tq+1],sc,sh)), 0.f);
                        op[(size_t)tq*84800] = f2bf(r);
                    }
                } else if (p == 1) {
                    const float w0_ = k3[(g*40+n)*3+0], w1_ = k3[(g*40+n)*3+1], w2_ = k3[(g*40+n)*3+2];
                    #pragma unroll
                    for (int tq = 0; tq < 16; ++tq) {
                        float a = yv[2*tq]*w1_;
                        if (tq > 0) a = fmaf(yv[2*tq-1], w0_, a);
                        a = fmaf(yv[2*tq+1], w2_, a);
                        float c2 = fmaf(yv[2*tq], w0_, yv[2*tq+1]*w1_);
                        if (tq < 15) c2 = fmaf(yv[2*tq+2], w2_, c2);
                        const float r = fmaxf(fmaxf(fmaf(a,sc,sh), fmaf(c2,sc,sh)), 0.f);
                        op[(size_t)tq*84800] = f2bf(r);
                    }
                } else if (p == 2) {
                    float wk[5];
                    #pragma unroll
                    for (int j = 0; j < 5; ++j) wk[j] = k5[(g*40+n)*5+j];
                    #pragma unroll
                    for (int tq = 0; tq < 16; ++tq) {
                        float vv[2];
                        #pragma unroll
                        for (int q = 0; q < 2; ++q) {
                            const int t = 2*tq + q;
                            float v = 0.f;
                            #pragma unroll
                            for (int j = 0; j < 5; ++j) {
                                const int ttp = t + j - 2;
                                if (ttp >= 0 && ttp < 32) v = fmaf(yv[ttp], wk[j], v);
                            }
                            vv[q] = v;
                        }
                        const float r = fmaxf(fmaxf(fmaf(vv[0],sc,sh), fmaf(vv[1],sc,sh)), 0.f);
                        op[(size_t)tq*84800] = f2bf(r);
                    }
                } else if (p == 3) {
                    float wk[7];
                    #pragma unroll
                    for (int j = 0; j < 7; ++j) wk[j] = k7[(g*40+n)*7+j];
                    #pragma unroll
                    for (int tq = 0; tq < 16; ++tq) {
                        float vv[2];
                        #pragma unroll
                        for (int q = 0; q < 2; ++q) {
                            const int t = 2*tq + q;
                            float v = 0.f;
                            #pragma unroll
                            for (int j = 0; j < 7; ++j) {
                                const int ttp = t + j - 3;
                                if (ttp >= 0 && ttp < 32) v = fmaf(yv[ttp], wk[j], v);
                            }
                            vv[q] = v;
                        }
                        const float r = fmaxf(fmaxf(fmaf(vv[0],sc,sh), fmaf(vv[1],sc,sh)), 0.f);
                        op[(size_t)tq*84800] = f2bf(r);
                    }
                } else {
                    #pragma unroll
                    for (int tq = 0; tq < 16; ++tq) {
                        const float v0 = fmaxf(yv[2*tq], yv[2*tq+1]);
                        const float v1 = fmaxf(yv[2*tq+1], yv[(2*tq+2 < 32) ? 2*tq+2 : 31]);
                        const float r = fmaxf(fmaxf(fmaf(v0,sc,sh), fmaf(v1,sc,sh)), 0.f);
                        op[(size_t)tq*84800] = f2bf(r);
                    }
                }
            }
        }
    }
}

// ---------------------------------------------------------------------------
// Shuffle: read og bf16 group-major (g*200+pq) -> write f32 ref order pq*8+g
// ---------------------------------------------------------------------------
__global__ __launch_bounds__(256) void tc_shuffle(const unsigned short* __restrict__ og,
                                                  float* __restrict__ o) {
    __shared__ unsigned short row[1600];
    const size_t base = (size_t)blockIdx.x * 1600;
    const int tid = threadIdx.x;
    if (tid < 200)
        *reinterpret_cast<ushort8*>(&row[tid*8]) =
            *reinterpret_cast<const ushort8*>(&og[base + (size_t)tid*8]);
    __syncthreads();
    #pragma unroll
    for (int it = 0; it < 2; ++it) {
        const int f4 = tid + it*256;
        if (f4 < 400) {
            const int c = f4*4;
            float4 v;
            v.x = bf2f(row[((c  ) & 7)*200 + ((c  ) >> 3)]);
            v.y = bf2f(row[((c+1) & 7)*200 + ((c+1) >> 3)]);
            v.z = bf2f(row[((c+2) & 7)*200 + ((c+2) >> 3)]);
            v.w = bf2f(row[((c+3) & 7)*200 + ((c+3) >> 3)]);
            *reinterpret_cast<float4*>(&o[base + (size_t)c]) = v;
        }
    }
}

extern "C" void kernel_launch(void* const* d_in, const int* in_sizes, int n_in,
                              void* d_out, int out_size, void* d_ws, size_t ws_size,
                              hipStream_t stream) {
    const float* x    = (const float*)d_in[0];
    const float* w0   = (const float*)d_in[1];
    const float* b0   = (const float*)d_in[2];
    const float* k3_0 = (const float*)d_in[3];
    const float* k5_0 = (const float*)d_in[4];
    const float* k7_0 = (const float*)d_in[5];
    const float* g0   = (const float*)d_in[6];
    const float* be0  = (const float*)d_in[7];
    const float* mu0  = (const float*)d_in[8];
    const float* v0   = (const float*)d_in[9];
    const float* w1   = (const float*)d_in[10];
    const float* b1   = (const float*)d_in[11];
    const float* k3_1 = (const float*)d_in[12];
    const float* k5_1 = (const float*)d_in[13];
    const float* k7_1 = (const float*)d_in[14];
    const float* g1   = (const float*)d_in[15];
    const float* be1  = (const float*)d_in[16];
    const float* mu1  = (const float*)d_in[17];
    const float* v1   = (const float*)d_in[18];

    // workspace layout (u16 units) -- total ~118 MB
    const size_t n_zb   = 34734080;     // 16*32*53*1280
    const size_t n_W0t  = 163840;       // 8*160*128
    const size_t n_W1t  = 256000;       // 8*200*160
    const size_t n_extb = 2097152;      // 16*2*64*1024

    unsigned short* zb   = (unsigned short*)d_ws;
    unsigned short* W0t  = zb + n_zb;
    unsigned short* W1t  = W0t + n_W0t;
    unsigned short* extb = W1t + n_W1t;
    unsigned short* og   = extb + n_extb;

    tc_prep_reduce0<<<1024 + 1640, 256, 0, stream>>>(x, extb, w0, w1, W0t, W1t);
    tc_layer0 <<<416*8, 512, 0, stream>>>(x, extb, W0t, b0, k3_0, k5_0,
                                          k7_0, g0, be0, mu0, v0, zb);
    tc_reduce1<<<16*32, 320, 0, stream>>>(zb);
    tc_layer1 <<<224*8, 512, 0, stream>>>(zb, W1t, b1, k3_1, k5_1, k7_1,
                                          g1, be1, mu1, v1, og);
    tc_shuffle<<<16*16*53, 256, 0, stream>>>(og, (float*)d_out);
}

// Round 12
// 236.775 us; speedup vs baseline: 2.2329x; 1.0483x over previous
//
#include <hip/hip_runtime.h>
#include <hip/hip_bf16.h>

#define EPSBN 1e-3f

typedef __attribute__((ext_vector_type(8))) short bf16x8;
typedef __attribute__((ext_vector_type(8))) unsigned short ushort8;
typedef __attribute__((ext_vector_type(4))) float f32x4;

// ---------------------------------------------------------------------------
//   x    : (16, 64, 49, 1024) f32
//   extb : (16, 2, 64, 1024)  bf16   [slot 0: max over s, slot 1: mean]
//   zb2  : (16, 32, 53, 1280) bf16   GROUP-MAJOR ch = g0*160 + (p*32+n);
//                                    s<51 by layer0, s=51,52 by reduce1
//   W0t  : bf16 [8 g][160 n][128 k]
//   W1t  : bf16 [8 g][200 n][160 k-permuted] (kref = (k%20)*8 + k/20)
//   og   : (16, 16, 53, 1600) bf16   group-major layer1 output
//   out  : (16, 16, 53, 1600) f32    ref channel order (pq*8+g), by tc_shuffle
// ---------------------------------------------------------------------------

__device__ __forceinline__ float bf2f(unsigned short u) {
    union { unsigned int i; float f; } c; c.i = (unsigned int)u << 16; return c.f;
}
__device__ __forceinline__ unsigned short f2bf(float f) {
    union { float f; unsigned int i; } c; c.f = f;
    unsigned int r = c.i + 0x7FFF + ((c.i >> 16) & 1);   // RNE
    return (unsigned short)(r >> 16);
}

// ---------------------------------------------------------------------------
// Combined: blocks 0..1023 = reduce0 (max/mean over s -> extb);
//           blocks 1024..2663 = weight transpose prep.
// ---------------------------------------------------------------------------
__global__ __launch_bounds__(256) void tc_prep_reduce0(
    const float* __restrict__ x, unsigned short* __restrict__ extb,
    const float* __restrict__ w0, const float* __restrict__ w1,
    unsigned short* __restrict__ W0t, unsigned short* __restrict__ W1t)
{
    if (blockIdx.x < 1024) {
        const int bt = blockIdx.x;              // b*64+t
        const int b  = bt >> 6, t = bt & 63;
        const int c  = threadIdx.x * 4;
        const float4* src = reinterpret_cast<const float4*>(x + (size_t)bt * 49 * 1024 + c);
        float4 v = src[0];
        float mx0 = v.x, mx1 = v.y, mx2 = v.z, mx3 = v.w;
        float sm0 = v.x, sm1 = v.y, sm2 = v.z, sm3 = v.w;
        for (int s = 1; s < 49; ++s) {
            float4 u = src[(size_t)s * 256];
            mx0 = fmaxf(mx0, u.x); sm0 += u.x;
            mx1 = fmaxf(mx1, u.y); sm1 += u.y;
            mx2 = fmaxf(mx2, u.z); sm2 += u.z;
            mx3 = fmaxf(mx3, u.w); sm3 += u.w;
        }
        const float inv = 1.0f / 49.0f;
        ushort4 omx, omn;
        omx.x=f2bf(mx0); omx.y=f2bf(mx1); omx.z=f2bf(mx2); omx.w=f2bf(mx3);
        omn.x=f2bf(sm0*inv); omn.y=f2bf(sm1*inv); omn.z=f2bf(sm2*inv); omn.w=f2bf(sm3*inv);
        *reinterpret_cast<ushort4*>(&extb[((size_t)(b*2 + 0)*64 + t)*1024 + c]) = omx;
        *reinterpret_cast<ushort4*>(&extb[((size_t)(b*2 + 1)*64 + t)*1024 + c]) = omn;
    } else {
        const int idx = (blockIdx.x - 1024) * 256 + threadIdx.x;
        if (idx < 163840) {                         // 8*160*128
            const int g   = idx / 20480;
            const int rem = idx - g*20480;
            const int n   = rem >> 7;
            const int k   = rem & 127;
            const int p   = n >> 5, nn = n & 31;
            W0t[idx] = f2bf(w0[(((size_t)p*8 + g)*128 + k)*32 + nn]);
        } else if (idx < 163840 + 256000) {         // 8*200*160
            const int i2  = idx - 163840;
            const int g   = i2 / 32000;
            const int rem = i2 - g*32000;
            const int n   = rem / 160;
            const int k   = rem - n*160;
            const int kref = (k % 20)*8 + k/20;
            const int p   = n / 40, nn = n - p*40;
            W1t[i2] = f2bf(w1[(((size_t)p*8 + g)*160 + kref)*40 + nn]);
        }
    }
}

// ---------------------------------------------------------------------------
// Layer 0: block (b, s-pair, g).  M = 128 rows = 2 s-columns x 64 t.
// 8 waves (512 thr).  Epilogue per t-half: yw[40] window, STATIC per-branch
// indices (p-branches kept separate -> no scratch), VGPR <= 85 -> 3 blk/CU.
// ---------------------------------------------------------------------------
__global__ __launch_bounds__(512, 6) void tc_layer0(
    const float* __restrict__ x, const unsigned short* __restrict__ extb,
    const unsigned short* __restrict__ W0t, const float* __restrict__ bias,
    const float* __restrict__ k3, const float* __restrict__ k5,
    const float* __restrict__ k7,
    const float* __restrict__ gam, const float* __restrict__ bet,
    const float* __restrict__ mu, const float* __restrict__ var,
    unsigned short* __restrict__ zb)
{
    const int tid = threadIdx.x;
    const int g   = blockIdx.x / 416;       // 416 = 16 b * 26 s-pairs; 416%8==0
    const int rem = blockIdx.x % 416;
    const int sp  = rem % 26;
    const int b   = rem / 26;
    const int s0  = sp*2;
    const int has1 = (s0 + 1 < 51);

    __shared__ __align__(16) unsigned short lds[128*136 + 160*40];  // 23808 u16 = 46.5KB
    unsigned short* AtU = lds;              // [128][136] bf16 (rows 0-63: s0, 64-127: s1)
    unsigned short* WtU = lds + 128*136;    // [160][40] bf16 (32-k chunk)
    unsigned short* Ytb = lds;              // [160][134] bf16 overlay (21440 u16)

    // ---- stage At (128 rows x 128 k) f32 -> bf16 (ext rows from extb) ----
    #pragma unroll
    for (int it = 0; it < 4; ++it) {
        const int fid = tid + it*512;           // < 2048
        const int row = fid >> 4;
        const int ch8 = (fid & 15) * 8;
        const int t   = row & 63;
        const int s   = (row < 64) ? s0 : (has1 ? s0+1 : s0);
        ushort8 u;
        if (s < 49) {
            const float* sp_ = x + ((size_t)(b*64 + t)*49 + s)*1024 + g*128 + ch8;
            const float4 f0 = *reinterpret_cast<const float4*>(sp_);
            const float4 f1 = *reinterpret_cast<const float4*>(sp_ + 4);
            u[0]=f2bf(f0.x); u[1]=f2bf(f0.y); u[2]=f2bf(f0.z); u[3]=f2bf(f0.w);
            u[4]=f2bf(f1.x); u[5]=f2bf(f1.y); u[6]=f2bf(f1.z); u[7]=f2bf(f1.w);
        } else {
            u = *reinterpret_cast<const ushort8*>(
                &extb[((size_t)(b*2 + (s-49))*64 + t)*1024 + g*128 + ch8]);
        }
        *reinterpret_cast<ushort8*>(&AtU[row*136 + ch8]) = u;
    }

    const int lane = tid & 63;
    const int wid  = tid >> 6;              // t-tile 0..7 over M=128
    const int fr   = lane & 15;
    const int kb   = lane >> 4;

    f32x4 zero = {0.f, 0.f, 0.f, 0.f};
    f32x4 acc[10];
    #pragma unroll
    for (int i = 0; i < 10; ++i) acc[i] = zero;

    for (int kc = 0; kc < 4; ++kc) {
        __syncthreads();
        #pragma unroll
        for (int it = 0; it < 2; ++it) {        // stage 160 n x 32 k
            const int gi = tid + it*512;        // < 640
            if (gi < 640) {
                const int n = gi >> 2, part = (gi & 3) * 8;
                *reinterpret_cast<ushort8*>(&WtU[n*40 + part]) =
                    *reinterpret_cast<const ushort8*>(
                        &W0t[((size_t)g*160 + n)*128 + kc*32 + part]);
            }
        }
        __syncthreads();
        const bf16x8 bfrag = *reinterpret_cast<const bf16x8*>(
            &AtU[(wid*16 + fr)*136 + kc*32 + kb*8]);
        #pragma unroll
        for (int nt = 0; nt < 10; ++nt) {
            const bf16x8 afrag = *reinterpret_cast<const bf16x8*>(
                &WtU[(nt*16 + fr)*40 + kb*8]);
            acc[nt] = __builtin_amdgcn_mfma_f32_16x16x32_bf16(afrag, bfrag, acc[nt], 0, 0, 0);
        }
    }
    __syncthreads();
    // D: row(n) = nt*16 + kb*4 + r, col = wid*16 + fr  (cols 0-63: s0, 64-127: s1)
    #pragma unroll
    for (int nt = 0; nt < 10; ++nt)
        #pragma unroll
        for (int r = 0; r < 4; ++r)
            Ytb[(nt*16 + kb*4 + r)*134 + wid*16 + fr] = f2bf(acc[nt][r]);
    __syncthreads();

    // ---- epilogue: 640 tasks = 160 ch x 2 s x 2 t-halves.
    //      yw[i] = y(t0+i) + bias (0 outside [0,64)); t0 = th*32-4.
    //      tq = th*16 + q2; y-index of (tq,q) in window = 2*q2 + 4 + q.
    #pragma unroll
    for (int it2 = 0; it2 < 2; ++it2) {
        const int task = tid + it2*512;
        if (task < 640) {
            const int ch   = task % 160;
            const int rest = task / 160;        // 0..3
            const int sIdx = rest >> 1;
            const int th   = rest & 1;
            if (!sIdx || has1) {
                const int s  = s0 + sIdx;
                const int p  = ch >> 5, n = ch & 31;
                const int pi = (p*8 + g)*32 + n;
                const float bsv = bias[pi];
                const float sc  = gam[pi]*rsqrtf(var[pi]+EPSBN);
                const float sh  = bet[pi] - mu[pi]*sc;
                const int t0 = th*32 - 4;
                float yw[40];
                #pragma unroll
                for (int i = 0; i < 40; i += 2) {
                    const int t = t0 + i;
                    if (t >= 0 && t < 64) {
                        const unsigned int w2 = *reinterpret_cast<const unsigned int*>(
                            &Ytb[ch*134 + sIdx*64 + t]);
                        yw[i]   = bf2f((unsigned short)(w2 & 0xffffu)) + bsv;
                        yw[i+1] = bf2f((unsigned short)(w2 >> 16)) + bsv;
                    } else { yw[i] = 0.f; yw[i+1] = 0.f; }
                }
                unsigned short* zp = zb + ((size_t)(b*32)*53 + s)*1280 + g*160 + ch
                                   + (size_t)(th*16)*67840;
                if (p == 0) {
                    #pragma unroll
                    for (int q2 = 0; q2 < 16; ++q2) {
                        const float r = fmaxf(fmaxf(fmaf(yw[2*q2+4],sc,sh),
                                                    fmaf(yw[2*q2+5],sc,sh)), 0.f);
                        zp[(size_t)q2*67840] = f2bf(r);
                    }
                } else if (p == 1) {
                    float wk[3];
                    #pragma unroll
                    for (int j = 0; j < 3; ++j) wk[j] = k3[(g*32+n)*3+j];
                    #pragma unroll
                    for (int q2 = 0; q2 < 16; ++q2) {
                        float vv[2];
                        #pragma unroll
                        for (int q = 0; q < 2; ++q) {
                            float v = 0.f;
                            #pragma unroll
                            for (int j = 0; j < 3; ++j)
                                v = fmaf(yw[2*q2 + q + j + 3], wk[j], v);
                            vv[q] = v;
                        }
                        const float r = fmaxf(fmaxf(fmaf(vv[0],sc,sh), fmaf(vv[1],sc,sh)), 0.f);
                        zp[(size_t)q2*67840] = f2bf(r);
                    }
                } else if (p == 2) {
                    float wk[5];
                    #pragma unroll
                    for (int j = 0; j < 5; ++j) wk[j] = k5[(g*32+n)*5+j];
                    #pragma unroll
                    for (int q2 = 0; q2 < 16; ++q2) {
                        float vv[2];
                        #pragma unroll
                        for (int q = 0; q < 2; ++q) {
                            float v = 0.f;
                            #pragma unroll
                            for (int j = 0; j < 5; ++j)
                                v = fmaf(yw[2*q2 + q + j + 2], wk[j], v);
                            vv[q] = v;
                        }
                        const float r = fmaxf(fmaxf(fmaf(vv[0],sc,sh), fmaf(vv[1],sc,sh)), 0.f);
                        zp[(size_t)q2*67840] = f2bf(r);
                    }
                } else if (p == 3) {
                    float wk[7];
                    #pragma unroll
                    for (int j = 0; j < 7; ++j) wk[j] = k7[(g*32+n)*7+j];
                    #pragma unroll
                    for (int q2 = 0; q2 < 16; ++q2) {
                        float vv[2];
                        #pragma unroll
                        for (int q = 0; q < 2; ++q) {
                            float v = 0.f;
                            #pragma unroll
                            for (int j = 0; j < 7; ++j)
                                v = fmaf(yw[2*q2 + q + j + 1], wk[j], v);
                            vv[q] = v;
                        }
                        const float r = fmaxf(fmaxf(fmaf(vv[0],sc,sh), fmaf(vv[1],sc,sh)), 0.f);
                        zp[(size_t)q2*67840] = f2bf(r);
                    }
                } else {
                    #pragma unroll
                    for (int q2 = 0; q2 < 16; ++q2) {
                        const int tq = th*16 + q2;
                        const float v0 = fmaxf(yw[2*q2+4], yw[2*q2+5]);
                        const float vb = (2*tq+2 < 64) ? yw[2*q2+6] : yw[35];
                        const float v1 = fmaxf(yw[2*q2+5], vb);
                        const float r = fmaxf(fmaxf(fmaf(v0,sc,sh), fmaf(v1,sc,sh)), 0.f);
                        zp[(size_t)q2*67840] = f2bf(r);
                    }
                }
            }
        }
    }
}

// ---------------------------------------------------------------------------
// reduce1: fills zb2 columns s=51 (max) and s=52 (mean) per (b,tq) row.
// ---------------------------------------------------------------------------
__global__ __launch_bounds__(320) void tc_reduce1(unsigned short* __restrict__ zb) {
    const int bt = blockIdx.x;              // b*32+tq
    const int c  = threadIdx.x * 4;         // 0..1276
    unsigned short* base = zb + (size_t)bt * 67840;
    ushort4 u = *reinterpret_cast<const ushort4*>(&base[c]);
    float v0 = bf2f(u.x), v1 = bf2f(u.y), v2 = bf2f(u.z), v3 = bf2f(u.w);
    float mx0 = v0, mx1 = v1, mx2 = v2, mx3 = v3;
    float sm0 = v0, sm1 = v1, sm2 = v2, sm3 = v3;
    for (int s = 1; s < 51; ++s) {
        ushort4 w = *reinterpret_cast<const ushort4*>(&base[(size_t)s*1280 + c]);
        v0 = bf2f(w.x); v1 = bf2f(w.y); v2 = bf2f(w.z); v3 = bf2f(w.w);
        mx0 = fmaxf(mx0, v0); sm0 += v0;
        mx1 = fmaxf(mx1, v1); sm1 += v1;
        mx2 = fmaxf(mx2, v2); sm2 += v2;
        mx3 = fmaxf(mx3, v3); sm3 += v3;
    }
    const float inv = 1.0f / 51.0f;
    ushort4 o;
    o.x = f2bf(mx0); o.y = f2bf(mx1); o.z = f2bf(mx2); o.w = f2bf(mx3);
    *reinterpret_cast<ushort4*>(&base[(size_t)51*1280 + c]) = o;
    o.x = f2bf(sm0*inv); o.y = f2bf(sm1*inv); o.z = f2bf(sm2*inv); o.w = f2bf(sm3*inv);
    *reinterpret_cast<ushort4*>(&base[(size_t)52*1280 + c]) = o;
}

// ---------------------------------------------------------------------------
// Layer 1: block (b, s-quad, g).  M = 128 rows = 4 s-columns x 32 t.
// LDS diet: At staged in two k-chunks; Ytb stride 130 (65 dw, odd).
// ---------------------------------------------------------------------------
__global__ __launch_bounds__(512, 4) void tc_layer1(
    const unsigned short* __restrict__ zbi,
    const unsigned short* __restrict__ W1t, const float* __restrict__ bias,
    const float* __restrict__ k3, const float* __restrict__ k5,
    const float* __restrict__ k7,
    const float* __restrict__ gam, const float* __restrict__ bet,
    const float* __restrict__ mu, const float* __restrict__ var,
    unsigned short* __restrict__ og)
{
    const int tid = threadIdx.x;
    const int g   = blockIdx.x / 224;       // 224 = 16 b * 14 s-quads; 224%8==0
    const int rem = blockIdx.x % 224;
    const int sq  = rem % 14;
    const int b   = rem / 14;
    const int s0  = sq*4;
    const int ns  = (53 - s0 < 4) ? (53 - s0) : 4;

    __shared__ __align__(16) unsigned short lds[26000];     // 50.8 KB
    unsigned short* AhU = lds;              // h1: [128][96] stride 104; h2: [128][64] stride 72
    unsigned short* WtU = lds + 13312;      // [208][40] bf16 (rows 200-207 zero)
    unsigned short* Ytb = lds;              // [200][130] bf16 overlay (26000 u16)

    if (tid < 40) {
        ushort8 z8 = {0,0,0,0,0,0,0,0};
        const int r = tid / 5, cp = tid - r*5;
        *reinterpret_cast<ushort8*>(&WtU[(200 + r)*40 + cp*8]) = z8;
    }

    // ---- gather At half 1: 128 rows x segs 0..23 (k 0..95) ----
    #pragma unroll
    for (int it = 0; it < 6; ++it) {
        const int fid = tid + it*512;           // < 3072
        const int row = fid / 24;
        const int seg = fid - row*24;           // 0..23
        const int gg  = seg / 5, q = seg - gg*5;
        const int ch  = gg*160 + g*20 + q*4;
        const int sl  = row >> 5;
        const int s   = s0 + ((sl < ns) ? sl : 0);
        const int t   = row & 31;
        const unsigned short* src = zbi + ((size_t)(b*32 + t)*53 + s)*1280 + ch;
        *reinterpret_cast<ushort4*>(&AhU[row*104 + seg*4]) =
            *reinterpret_cast<const ushort4*>(src);
    }

    const int lane = tid & 63;
    const int wid  = tid >> 6;              // t-tile 0..7 over M=128
    const int fr   = lane & 15;
    const int kb   = lane >> 4;

    f32x4 zero = {0.f, 0.f, 0.f, 0.f};
    f32x4 acc[13];
    #pragma unroll
    for (int i = 0; i < 13; ++i) acc[i] = zero;

    for (int kc = 0; kc < 5; ++kc) {
        __syncthreads();
        if (kc == 3) {
            // ---- gather At half 2: 128 rows x segs 24..39 (k 96..159) ----
            #pragma unroll
            for (int it = 0; it < 4; ++it) {
                const int fid = tid + it*512;       // < 2048
                const int row = fid >> 4;
                const int s24 = fid & 15;           // seg-24
                const int seg = s24 + 24;
                const int gg  = seg / 5, q = seg - gg*5;
                const int ch  = gg*160 + g*20 + q*4;
                const int sl  = row >> 5;
                const int s   = s0 + ((sl < ns) ? sl : 0);
                const int t   = row & 31;
                const unsigned short* src = zbi + ((size_t)(b*32 + t)*53 + s)*1280 + ch;
                *reinterpret_cast<ushort4*>(&AhU[row*72 + s24*4]) =
                    *reinterpret_cast<const ushort4*>(src);
            }
        }
        #pragma unroll
        for (int it = 0; it < 2; ++it) {        // stage 200 n x 32 k
            const int gi = tid + it*512;        // < 800
            if (gi < 800) {
                const int n = gi >> 2, part = (gi & 3) * 8;
                *reinterpret_cast<ushort8*>(&WtU[n*40 + part]) =
                    *reinterpret_cast<const ushort8*>(
                        &W1t[((size_t)g*200 + n)*160 + kc*32 + part]);
            }
        }
        __syncthreads();
        const bf16x8 bfrag = (kc < 3)
            ? *reinterpret_cast<const bf16x8*>(&AhU[(wid*16 + fr)*104 + kc*32 + kb*8])
            : *reinterpret_cast<const bf16x8*>(&AhU[(wid*16 + fr)*72 + (kc-3)*32 + kb*8]);
        #pragma unroll
        for (int nt = 0; nt < 13; ++nt) {
            const bf16x8 afrag = *reinterpret_cast<const bf16x8*>(
                &WtU[(nt*16 + fr)*40 + kb*8]);
            acc[nt] = __builtin_amdgcn_mfma_f32_16x16x32_bf16(afrag, bfrag, acc[nt], 0, 0, 0);
        }
    }
    __syncthreads();
    #pragma unroll
    for (int nt = 0; nt < 13; ++nt) {
        #pragma unroll
        for (int r = 0; r < 4; ++r) {
            const int n = nt*16 + kb*4 + r;
            if (n < 200) Ytb[n*130 + wid*16 + fr] = f2bf(acc[nt][r]);
        }
    }
    __syncthreads();

    // ---- epilogue: 800 tasks = 200 ch x 4 s ----
    #pragma unroll
    for (int it = 0; it < 2; ++it) {
        const int task = tid + it*512;
        if (task < 800) {
            const int sIdx = task / 200;
            const int ch   = task - sIdx*200;
            if (sIdx < ns) {
                const int s  = s0 + sIdx;
                const int p  = ch / 40, n = ch - p*40;
                const int pi = (p*8 + g)*40 + n;
                const float bsv = bias[pi];
                const float sc  = gam[pi]*rsqrtf(var[pi]+EPSBN);
                const float sh  = bet[pi] - mu[pi]*sc;
                float yv[32];
                #pragma unroll
                for (int i = 0; i < 16; ++i) {
                    const unsigned int w2 = *reinterpret_cast<const unsigned int*>(
                        &Ytb[ch*130 + sIdx*32 + i*2]);
                    yv[2*i]   = bf2f((unsigned short)(w2 & 0xffffu)) + bsv;
                    yv[2*i+1] = bf2f((unsigned short)(w2 >> 16)) + bsv;
                }
                unsigned short* op = og + ((size_t)(b*16)*53 + s)*1600 + g*200 + ch;
                if (p == 0) {
                    #pragma unroll
                    for (int tq = 0; tq < 16; ++tq) {
                        const float r = fmaxf(fmaxf(fmaf(yv[2*tq],sc,sh), fmaf(yv[2*tq+1],sc,sh)), 0.f);
                        op[(size_t)tq*84800] = f2bf(r);
                    }
                } else if (p == 1) {
                    const float w0_ = k3[(g*40+n)*3+0], w1_ = k3[(g*40+n)*3+1], w2_ = k3[(g*40+n)*3+2];
                    #pragma unroll
                    for (int tq = 0; tq < 16; ++tq) {
                        float a = yv[2*tq]*w1_;
                        if (tq > 0) a = fmaf(yv[2*tq-1], w0_, a);
                        a = fmaf(yv[2*tq+1], w2_, a);
                        float c2 = fmaf(yv[2*tq], w0_, yv[2*tq+1]*w1_);
                        if (tq < 15) c2 = fmaf(yv[2*tq+2], w2_, c2);
                        const float r = fmaxf(fmaxf(fmaf(a,sc,sh), fmaf(c2,sc,sh)), 0.f);
                        op[(size_t)tq*84800] = f2bf(r);
                    }
                } else if (p == 2) {
                    float wk[5];
                    #pragma unroll
                    for (int j = 0; j < 5; ++j) wk[j] = k5[(g*40+n)*5+j];
                    #pragma unroll
                    for (int tq = 0; tq < 16; ++tq) {
                        float vv[2];
                        #pragma unroll
                        for (int q = 0; q < 2; ++q) {
                            const int t = 2*tq + q;
                            float v = 0.f;
                            #pragma unroll
                            for (int j = 0; j < 5; ++j) {
                                const int ttp = t + j - 2;
                                if (ttp >= 0 && ttp < 32) v = fmaf(yv[ttp], wk[j], v);
                            }
                            vv[q] = v;
                        }
                        const float r = fmaxf(fmaxf(fmaf(vv[0],sc,sh), fmaf(vv[1],sc,sh)), 0.f);
                        op[(size_t)tq*84800] = f2bf(r);
                    }
                } else if (p == 3) {
                    float wk[7];
                    #pragma unroll
                    for (int j = 0; j < 7; ++j) wk[j] = k7[(g*40+n)*7+j];
                    #pragma unroll
                    for (int tq = 0; tq < 16; ++tq) {
                        float vv[2];
                        #pragma unroll
                        for (int q = 0; q < 2; ++q) {
                            const int t = 2*tq + q;
                            float v = 0.f;
                            #pragma unroll
                            for (int j = 0; j < 7; ++j) {
                                const int ttp = t + j - 3;
                                if (ttp >= 0 && ttp < 32) v = fmaf(yv[ttp], wk[j], v);
                            }
                            vv[q] = v;
                        }
                        const float r = fmaxf(fmaxf(fmaf(vv[0],sc,sh), fmaf(vv[1],sc,sh)), 0.f);
                        op[(size_t)tq*84800] = f2bf(r);
                    }
                } else {
                    #pragma unroll
                    for (int tq = 0; tq < 16; ++tq) {
                        const float v0 = fmaxf(yv[2*tq], yv[2*tq+1]);
                        const float v1 = fmaxf(yv[2*tq+1], yv[(2*tq+2 < 32) ? 2*tq+2 : 31]);
                        const float r = fmaxf(fmaxf(fmaf(v0,sc,sh), fmaf(v1,sc,sh)), 0.f);
                        op[(size_t)tq*84800] = f2bf(r);
                    }
                }
            }
        }
    }
}

// ---------------------------------------------------------------------------
// Shuffle: read og bf16 group-major (g*200+pq) -> write f32 ref order pq*8+g
// ---------------------------------------------------------------------------
__global__ __launch_bounds__(256) void tc_shuffle(const unsigned short* __restrict__ og,
                                                  float* __restrict__ o) {
    __shared__ unsigned short row[1600];
    const size_t base = (size_t)blockIdx.x * 1600;
    const int tid = threadIdx.x;
    if (tid < 200)
        *reinterpret_cast<ushort8*>(&row[tid*8]) =
            *reinterpret_cast<const ushort8*>(&og[base + (size_t)tid*8]);
    __syncthreads();
    #pragma unroll
    for (int it = 0; it < 2; ++it) {
        const int f4 = tid + it*256;
        if (f4 < 400) {
            const int c = f4*4;
            float4 v;
            v.x = bf2f(row[((c  ) & 7)*200 + ((c  ) >> 3)]);
            v.y = bf2f(row[((c+1) & 7)*200 + ((c+1) >> 3)]);
            v.z = bf2f(row[((c+2) & 7)*200 + ((c+2) >> 3)]);
            v.w = bf2f(row[((c+3) & 7)*200 + ((c+3) >> 3)]);
            *reinterpret_cast<float4*>(&o[base + (size_t)c]) = v;
        }
    }
}

extern "C" void kernel_launch(void* const* d_in, const int* in_sizes, int n_in,
                              void* d_out, int out_size, void* d_ws, size_t ws_size,
                              hipStream_t stream) {
    const float* x    = (const float*)d_in[0];
    const float* w0   = (const float*)d_in[1];
    const float* b0   = (const float*)d_in[2];
    const float* k3_0 = (const float*)d_in[3];
    const float* k5_0 = (const float*)d_in[4];
    const float* k7_0 = (const float*)d_in[5];
    const float* g0   = (const float*)d_in[6];
    const float* be0  = (const float*)d_in[7];
    const float* mu0  = (const float*)d_in[8];
    const float* v0   = (const float*)d_in[9];
    const float* w1   = (const float*)d_in[10];
    const float* b1   = (const float*)d_in[11];
    const float* k3_1 = (const float*)d_in[12];
    const float* k5_1 = (const float*)d_in[13];
    const float* k7_1 = (const float*)d_in[14];
    const float* g1   = (const float*)d_in[15];
    const float* be1  = (const float*)d_in[16];
    const float* mu1  = (const float*)d_in[17];
    const float* v1   = (const float*)d_in[18];

    // workspace layout (u16 units) -- total ~118 MB
    const size_t n_zb   = 34734080;     // 16*32*53*1280
    const size_t n_W0t  = 163840;       // 8*160*128
    const size_t n_W1t  = 256000;       // 8*200*160
    const size_t n_extb = 2097152;      // 16*2*64*1024

    unsigned short* zb   = (unsigned short*)d_ws;
    unsigned short* W0t  = zb + n_zb;
    unsigned short* W1t  = W0t + n_W0t;
    unsigned short* extb = W1t + n_W1t;
    unsigned short* og   = extb + n_extb;

    tc_prep_reduce0<<<1024 + 1640, 256, 0, stream>>>(x, extb, w0, w1, W0t, W1t);
    tc_layer0 <<<416*8, 512, 0, stream>>>(x, extb, W0t, b0, k3_0, k5_0,
                                          k7_0, g0, be0, mu0, v0, zb);
    tc_reduce1<<<16*32, 320, 0, stream>>>(zb);
    tc_layer1 <<<224*8, 512, 0, stream>>>(zb, W1t, b1, k3_1, k5_1, k7_1,
                                          g1, be1, mu1, v1, og);
    tc_shuffle<<<16*16*53, 256, 0, stream>>>(og, (float*)d_out);
}